// Round 14
// baseline (858.877 us; speedup 1.0000x reference)
//
#include <hip/hip_runtime.h>
#include <float.h>
#include <math.h>

namespace {

constexpr int NB = 16;
constexpr int NP = 2048;
constexpr int KK = 20;
constexpr int TOT = NB * NP;   // 32768
constexpr int EBLK = 1024;     // edge pass grid

typedef short short8v __attribute__((ext_vector_type(8)));   // 8 bf16 (4 VGPRs)
typedef float f32x16 __attribute__((ext_vector_type(16)));

__device__ __forceinline__ float leaky(float v) { return fmaxf(v, 0.2f * v); }

__device__ __forceinline__ unsigned short bf16_rne(float x) {
    unsigned u = __float_as_uint(x);
    unsigned r = u + 0x7FFFu + ((u >> 16) & 1u);
    return (unsigned short)(r >> 16);
}
__device__ __forceinline__ float bf16_f(unsigned short h) {
    return __uint_as_float(((unsigned)h) << 16);
}
__device__ __forceinline__ unsigned mono_key(float d) {
    unsigned bits = __float_as_uint(d);
    return (bits & 0x80000000u) ? ~bits : (bits | 0x80000000u);
}
__device__ __forceinline__ unsigned short key16(float d) {
    return (unsigned short)(mono_key(d) >> 16);
}

// ---------------- pos -> pos4 (pad to 4) + squared norm ----------------
__global__ __launch_bounds__(256) void pos4sq_kernel(const float* __restrict__ pos,
                                                     float* __restrict__ pos4,
                                                     float* __restrict__ sq) {
    int i = blockIdx.x * 256 + threadIdx.x;
    if (i < TOT) {
        float x = pos[i * 3 + 0], y = pos[i * 3 + 1], z = pos[i * 3 + 2];
        pos4[i * 4 + 0] = x;
        pos4[i * 4 + 1] = y;
        pos4[i * 4 + 2] = z;
        pos4[i * 4 + 3] = 0.f;
        sq[i] = x * x + y * y + z * z;
    }
}

// ---------------- layer-1 fully fused kNN: batch slice in LDS, exact f32 keys ----------------
// Block = 4 waves = 16 queries; stages pos4+sq of the whole batch (40 KB LDS).
// Per query: exact keys from LDS (32/lane), lane-min bound B (>= true 20th),
// compact {key <= B} (cap 64), exact rank + stable tie emission. Fallback:
// exact selection on the register keys. No global keys traffic.
__global__ __launch_bounds__(256) void knn_l1_fused_kernel(const float* __restrict__ x,
                                                           const float* __restrict__ sq,
                                                           int* __restrict__ idx_out) {
    __shared__ float4 xs[NP];      // 32 KB
    __shared__ float sqs[NP];      // 8 KB
    __shared__ int scand[4][64];   // 1 KB
    const int tid = threadIdx.x;
    const int w = tid >> 6, lane = tid & 63;
    const int b = blockIdx.x >> 7;          // NP/16 = 128 chunks per batch
    const int chunk = blockIdx.x & 127;
    const int bofs = b * NP;
    for (int i = tid; i < NP; i += 256) {
        xs[i] = *reinterpret_cast<const float4*>(x + (size_t)(bofs + i) * 4);
        sqs[i] = sq[bofs + i];
    }
    __syncthreads();
    for (int qi = 0; qi < 4; ++qi) {
        const int qloc = chunk * 16 + w * 4 + qi;
        const float4 qv = xs[qloc];
        const float sqq = sqs[qloc];
        unsigned keys[32];
        unsigned lmn = 0xFFFFFFFFu;
        #pragma unroll
        for (int u = 0; u < 32; ++u) {
            const int m = u * 64 + lane;
            float4 c = xs[m];
            float dot = qv.x * c.x + qv.y * c.y + qv.z * c.z + qv.w * c.w;
            keys[u] = mono_key(sqq + sqs[m] - 2.f * dot);
            lmn = min(lmn, keys[u]);
        }
        // bound B = 20th-smallest lane-min (>= exact 20th of the row)
        unsigned lo = lmn, hi = lmn;
        #pragma unroll
        for (int s = 1; s < 64; s <<= 1) {
            lo = min(lo, __shfl_xor(lo, s));
            hi = max(hi, __shfl_xor(hi, s));
        }
        while (lo < hi) {
            unsigned mid = lo + ((hi - lo) >> 1);
            int c = __popcll(__ballot(lmn <= mid));
            if (c >= KK) hi = mid; else lo = mid + 1;
        }
        const unsigned B = lo;
        unsigned nl = 0;
        #pragma unroll
        for (int u = 0; u < 32; ++u) nl += (keys[u] <= B) ? 1u : 0u;
        unsigned sc = nl;
        #pragma unroll
        for (int s = 1; s < 64; s <<= 1) {
            unsigned t2 = __shfl_up(sc, s);
            if (lane >= s) sc += t2;
        }
        const int cnt = (int)__shfl(sc, 63);
        unsigned off = sc - nl;
        #pragma unroll
        for (int u = 0; u < 32; ++u) {
            if (keys[u] <= B) { if (off < 64u) scand[w][off] = u * 64 + lane; ++off; }
        }
        int* op = idx_out + (size_t)(bofs + qloc) * KK;
        if (cnt <= 64) {
            const int cl = (lane < cnt) ? scand[w][lane] : -1;
            unsigned key = 0xFFFFFFFFu;
            if (cl >= 0) {
                float4 c = xs[cl];
                float dot = qv.x * c.x + qv.y * c.y + qv.z * c.z + qv.w * c.w;
                key = mono_key(sqq + sqs[cl] - 2.f * dot);   // identical expression
            }
            unsigned klo = key, khi = key;
            #pragma unroll
            for (int s = 1; s < 64; s <<= 1) {
                klo = min(klo, __shfl_xor(klo, s));
                khi = max(khi, __shfl_xor(khi, s));
            }
            while (klo < khi) {
                unsigned mid = klo + ((khi - klo) >> 1);
                int c = __popcll(__ballot(key <= mid));
                if (c >= KK) khi = mid; else klo = mid + 1;
            }
            const unsigned Tx = klo;
            unsigned long long blt = __ballot(key < Tx);
            const int strict = __popcll(blt);
            if (key < Tx) {
                int o = __popcll(blt & ((1ull << lane) - 1ull));
                op[o] = bofs + cl;
            }
            const int rem = KK - strict;
            bool eq = (key == Tx) && (cl >= 0);
            bool done = false;
            for (int t = 0; t < rem; ++t) {   // ties ascending by global index
                int v = (eq && !done) ? cl : 0x7FFFFFFF;
                #pragma unroll
                for (int s = 1; s < 64; s <<= 1) v = min(v, __shfl_xor(v, s));
                if (eq && !done && cl == v) { op[strict + t] = bofs + cl; done = true; }
            }
        } else {
            // fallback: exact selection on register keys (rare)
            unsigned lo2 = lmn, hi2 = 0;
            #pragma unroll
            for (int u = 0; u < 32; ++u) hi2 = max(hi2, keys[u]);
            #pragma unroll
            for (int s = 1; s < 64; s <<= 1) {
                lo2 = min(lo2, __shfl_xor(lo2, s));
                hi2 = max(hi2, __shfl_xor(hi2, s));
            }
            while (lo2 < hi2) {
                unsigned mid = lo2 + ((hi2 - lo2) >> 1);
                int c = 0;
                #pragma unroll
                for (int u = 0; u < 32; ++u)
                    c += __popcll(__ballot(keys[u] <= mid));
                if (c >= KK) hi2 = mid; else lo2 = mid + 1;
            }
            const unsigned Tx = lo2;
            unsigned nl2 = 0;
            #pragma unroll
            for (int u = 0; u < 32; ++u) nl2 += (keys[u] < Tx) ? 1u : 0u;
            unsigned sc2 = nl2;
            #pragma unroll
            for (int s = 1; s < 64; s <<= 1) {
                unsigned t2 = __shfl_up(sc2, s);
                if (lane >= s) sc2 += t2;
            }
            unsigned cstrict = __shfl(sc2, 63);
            unsigned o = sc2 - nl2;
            #pragma unroll
            for (int u = 0; u < 32; ++u) {
                if (keys[u] < Tx) { op[o] = bofs + u * 64 + lane; ++o; }
            }
            int rem = KK - (int)cstrict;
            int ebase = (int)cstrict;
            #pragma unroll
            for (int u = 0; u < 32; ++u) {
                if (rem > 0) {
                    bool eq = (keys[u] == Tx);
                    unsigned long long bm = __ballot(eq);
                    int before = __popcll(bm & ((1ull << lane) - 1ull));
                    if (eq && before < rem) op[ebase + before] = bofs + u * 64 + lane;
                    int take = __popcll(bm);
                    if (take > rem) take = rem;
                    ebase += take;
                    rem -= take;
                }
            }
        }
    }
}

// ---------------- layers 2/3: MFMA bf16x3 distance -> 16-bit keys (transposed store) ----------------
__global__ __launch_bounds__(256) void dist_mfma16_kernel(const unsigned short* __restrict__ xh,
                                                          const unsigned short* __restrict__ xl,
                                                          int ch_off,
                                                          const float* __restrict__ sq,
                                                          int b0,
                                                          unsigned short* __restrict__ keys) {
    __shared__ __align__(16) unsigned short Ah[128 * 64];
    __shared__ __align__(16) unsigned short Al[128 * 64];
    __shared__ __align__(16) unsigned short Bh[128 * 64];
    __shared__ __align__(16) unsigned short Bl[128 * 64];
    const int tid = threadIdx.x;
    const int w = tid >> 6, lane = tid & 63;
    const int wr = w >> 1, wc = w & 1;
    const int tm = blockIdx.x >> 4, tn = blockIdx.x & 15;
    const int m0 = tm * 128, n0 = tn * 128;
    const int bofs = (b0 + blockIdx.y) * NP;
    for (int i = tid; i < 1024; i += 256) {
        const int r = i >> 3, slot = i & 7;
        const int ls = r * 64 + ((slot ^ (r & 7)) << 3);
        const size_t ga = (size_t)(bofs + m0 + r) * 256 + ch_off + slot * 8;
        const size_t gb = (size_t)(bofs + n0 + r) * 256 + ch_off + slot * 8;
        *reinterpret_cast<uint4*>(&Ah[ls]) = *reinterpret_cast<const uint4*>(&xh[ga]);
        *reinterpret_cast<uint4*>(&Al[ls]) = *reinterpret_cast<const uint4*>(&xl[ga]);
        *reinterpret_cast<uint4*>(&Bh[ls]) = *reinterpret_cast<const uint4*>(&xh[gb]);
        *reinterpret_cast<uint4*>(&Bl[ls]) = *reinterpret_cast<const uint4*>(&xl[gb]);
    }
    __syncthreads();
    const int h = lane >> 5;
    const int ar0 = wr * 64 + (lane & 31), ar1 = ar0 + 32;
    const int bc0 = wc * 64 + (lane & 31), bc1 = bc0 + 32;
    f32x16 acc00 = {}, acc01 = {}, acc10 = {}, acc11 = {};
    #pragma unroll
    for (int s = 0; s < 4; ++s) {
        const int sl = s * 2 + h;
        const int ia0 = ar0 * 64 + ((sl ^ (ar0 & 7)) << 3);
        const int ia1 = ar1 * 64 + ((sl ^ (ar1 & 7)) << 3);
        const int ib0 = bc0 * 64 + ((sl ^ (bc0 & 7)) << 3);
        const int ib1 = bc1 * 64 + ((sl ^ (bc1 & 7)) << 3);
        short8v a0h = *reinterpret_cast<const short8v*>(&Ah[ia0]);
        short8v a1h = *reinterpret_cast<const short8v*>(&Ah[ia1]);
        short8v a0l = *reinterpret_cast<const short8v*>(&Al[ia0]);
        short8v a1l = *reinterpret_cast<const short8v*>(&Al[ia1]);
        short8v b0h = *reinterpret_cast<const short8v*>(&Bh[ib0]);
        short8v b1h = *reinterpret_cast<const short8v*>(&Bh[ib1]);
        short8v b0l = *reinterpret_cast<const short8v*>(&Bl[ib0]);
        short8v b1l = *reinterpret_cast<const short8v*>(&Bl[ib1]);
        acc00 = __builtin_amdgcn_mfma_f32_32x32x16_bf16(a0h, b0h, acc00, 0, 0, 0);
        acc01 = __builtin_amdgcn_mfma_f32_32x32x16_bf16(a0h, b1h, acc01, 0, 0, 0);
        acc10 = __builtin_amdgcn_mfma_f32_32x32x16_bf16(a1h, b0h, acc10, 0, 0, 0);
        acc11 = __builtin_amdgcn_mfma_f32_32x32x16_bf16(a1h, b1h, acc11, 0, 0, 0);
        acc00 = __builtin_amdgcn_mfma_f32_32x32x16_bf16(a0h, b0l, acc00, 0, 0, 0);
        acc01 = __builtin_amdgcn_mfma_f32_32x32x16_bf16(a0h, b1l, acc01, 0, 0, 0);
        acc10 = __builtin_amdgcn_mfma_f32_32x32x16_bf16(a1h, b0l, acc10, 0, 0, 0);
        acc11 = __builtin_amdgcn_mfma_f32_32x32x16_bf16(a1h, b1l, acc11, 0, 0, 0);
        acc00 = __builtin_amdgcn_mfma_f32_32x32x16_bf16(a0l, b0h, acc00, 0, 0, 0);
        acc01 = __builtin_amdgcn_mfma_f32_32x32x16_bf16(a0l, b1h, acc01, 0, 0, 0);
        acc10 = __builtin_amdgcn_mfma_f32_32x32x16_bf16(a1l, b0h, acc10, 0, 0, 0);
        acc11 = __builtin_amdgcn_mfma_f32_32x32x16_bf16(a1l, b1h, acc11, 0, 0, 0);
    }
    const int colg0 = n0 + bc0;
    const int colg1 = n0 + bc1;
    const float sqc0 = sq[bofs + colg0];
    const float sqc1 = sq[bofs + colg1];
    unsigned short* kb = keys + (size_t)blockIdx.y * NP * NP;
    #pragma unroll
    for (int ai = 0; ai < 2; ++ai) {
        const f32x16& A0 = ai ? acc10 : acc00;
        const f32x16& A1 = ai ? acc11 : acc01;
        #pragma unroll
        for (int q = 0; q < 4; ++q) {
            const int rbase = wr * 64 + ai * 32 + 8 * q + 4 * h;   // frag row base
            float sr[4];
            #pragma unroll
            for (int j = 0; j < 4; ++j) sr[j] = sq[bofs + m0 + rbase + j];
            ushort4 s0, s1;
            s0.x = key16(sr[0] + sqc0 - 2.f * A0[q * 4 + 0]);
            s0.y = key16(sr[1] + sqc0 - 2.f * A0[q * 4 + 1]);
            s0.z = key16(sr[2] + sqc0 - 2.f * A0[q * 4 + 2]);
            s0.w = key16(sr[3] + sqc0 - 2.f * A0[q * 4 + 3]);
            s1.x = key16(sr[0] + sqc1 - 2.f * A1[q * 4 + 0]);
            s1.y = key16(sr[1] + sqc1 - 2.f * A1[q * 4 + 1]);
            s1.z = key16(sr[2] + sqc1 - 2.f * A1[q * 4 + 2]);
            s1.w = key16(sr[3] + sqc1 - 2.f * A1[q * 4 + 3]);
            *reinterpret_cast<ushort4*>(&kb[(size_t)colg0 * NP + m0 + rbase]) = s0;
            *reinterpret_cast<ushort4*>(&kb[(size_t)colg1 * NP + m0 + rbase]) = s1;
        }
    }
}

// ---------------- fused select16 + exact refine: wave per query (layers 2/3) ----------------
template <int D>
__global__ __launch_bounds__(256) void knn_sr_kernel(const unsigned short* __restrict__ keys,
                                                     int b0,
                                                     const float* __restrict__ xf, int ldx,
                                                     const float* __restrict__ sq,
                                                     int* __restrict__ idx_out) {
    constexpr int D4 = D / 4;
    __shared__ int scand[4][64];
    const int tid = threadIdx.x;
    const int w = tid >> 6, lane = tid & 63;
    const int ql = blockIdx.x * 4 + w;        // chunk-local query
    const int bc = ql / NP;
    const int bofs = (b0 + bc) * NP;
    const int q = b0 * NP + ql;               // global query
    const unsigned* kr = reinterpret_cast<const unsigned*>(keys) + (size_t)ql * (NP / 2);

    unsigned kv[16];
    #pragma unroll
    for (int v = 0; v < 16; ++v) kv[v] = kr[v * 64 + lane];

    unsigned lmn = 0xFFFFu;
    #pragma unroll
    for (int v = 0; v < 16; ++v) {
        lmn = min(lmn, kv[v] & 0xFFFFu);
        lmn = min(lmn, kv[v] >> 16);
    }
    unsigned lo = lmn, hi = lmn;
    #pragma unroll
    for (int s = 1; s < 64; s <<= 1) {
        lo = min(lo, __shfl_xor(lo, s));
        hi = max(hi, __shfl_xor(hi, s));
    }
    while (lo < hi) {
        unsigned mid = (lo + hi) >> 1;
        int c = __popcll(__ballot(lmn <= mid));
        if (c >= KK) hi = mid; else lo = mid + 1;
    }
    const unsigned T = min(lo + 6u, 0xFFFFu);   // B >= T16; +6 covers MFMA approx error

    unsigned nl = 0;
    #pragma unroll
    for (int v = 0; v < 16; ++v) {
        nl += ((kv[v] & 0xFFFFu) <= T) ? 1u : 0u;
        nl += ((kv[v] >> 16) <= T) ? 1u : 0u;
    }
    unsigned sc = nl;
    #pragma unroll
    for (int s = 1; s < 64; s <<= 1) {
        unsigned t2 = __shfl_up(sc, s);
        if (lane >= s) sc += t2;
    }
    const int cnt = (int)__shfl(sc, 63);
    unsigned off = sc - nl;
    #pragma unroll
    for (int v = 0; v < 16; ++v) {
        if ((kv[v] & 0xFFFFu) <= T) { if (off < 64u) scand[w][off] = bofs + (v * 64 + lane) * 2; ++off; }
        if ((kv[v] >> 16) <= T)     { if (off < 64u) scand[w][off] = bofs + (v * 64 + lane) * 2 + 1; ++off; }
    }

    float4 qv[D4];
    const float4* xq4 = reinterpret_cast<const float4*>(xf + (size_t)q * ldx);
    #pragma unroll
    for (int k = 0; k < D4; ++k) qv[k] = xq4[k];
    const float sqq = sq[q];
    int* op = idx_out + (size_t)q * KK;

    if (cnt <= 64) {
        const int cidx = (lane < cnt) ? scand[w][lane] : -1;
        unsigned key = 0xFFFFFFFFu;
        if (cidx >= 0) {
            const float4* xc4 = reinterpret_cast<const float4*>(xf + (size_t)cidx * ldx);
            float acc = 0.f;
            #pragma unroll
            for (int k = 0; k < D4; ++k) {
                float4 c = xc4[k];
                acc += qv[k].x * c.x; acc += qv[k].y * c.y;
                acc += qv[k].z * c.z; acc += qv[k].w * c.w;
            }
            key = mono_key(sqq + sq[cidx] - 2.f * acc);
        }
        unsigned klo = key, khi = key;
        #pragma unroll
        for (int s = 1; s < 64; s <<= 1) {
            klo = min(klo, __shfl_xor(klo, s));
            khi = max(khi, __shfl_xor(khi, s));
        }
        while (klo < khi) {
            unsigned mid = klo + ((khi - klo) >> 1);
            int c = __popcll(__ballot(key <= mid));
            if (c >= KK) khi = mid; else klo = mid + 1;
        }
        const unsigned Tx = klo;
        unsigned long long blt = __ballot(key < Tx);
        const int strict = __popcll(blt);
        if (key < Tx) {
            int o = __popcll(blt & ((1ull << lane) - 1ull));
            op[o] = cidx;
        }
        const int rem = KK - strict;
        bool eq = (key == Tx) && (cidx >= 0);
        bool done = false;
        for (int t = 0; t < rem; ++t) {   // emit ties in ascending global index order
            int v = (eq && !done) ? cidx : 0x7FFFFFFF;
            #pragma unroll
            for (int s = 1; s < 64; s <<= 1) v = min(v, __shfl_xor(v, s));
            if (eq && !done && cidx == v) { op[strict + t] = cidx; done = true; }
        }
    } else {
        // fallback: exact full-row scan (deterministic; ~never taken)
        unsigned keysr[32];
        for (int u = 0; u < 32; ++u) {
            const int c = bofs + u * 64 + lane;
            const float4* xc4 = reinterpret_cast<const float4*>(xf + (size_t)c * ldx);
            float acc = 0.f;
            #pragma unroll
            for (int k = 0; k < D4; ++k) {
                float4 cv = xc4[k];
                acc += qv[k].x * cv.x; acc += qv[k].y * cv.y;
                acc += qv[k].z * cv.z; acc += qv[k].w * cv.w;
            }
            keysr[u] = mono_key(sqq + sq[c] - 2.f * acc);
        }
        unsigned lmn2 = 0xFFFFFFFFu;
        #pragma unroll
        for (int u = 0; u < 32; ++u) lmn2 = min(lmn2, keysr[u]);
        unsigned M2 = lmn2, lo2 = lmn2;
        #pragma unroll
        for (int s = 1; s < 64; s <<= 1) {
            unsigned tM = __shfl_xor(M2, s);
            unsigned tl = __shfl_xor(lo2, s);
            M2 = max(M2, tM);
            lo2 = min(lo2, tl);
        }
        unsigned hi2 = M2;
        while (lo2 < hi2) {
            unsigned mid = lo2 + ((hi2 - lo2) >> 1);
            int c = 0;
            #pragma unroll
            for (int u = 0; u < 32; ++u)
                c += __popcll(__ballot(keysr[u] <= mid));
            if (c >= KK) hi2 = mid; else lo2 = mid + 1;
        }
        const unsigned Tx = lo2;
        unsigned nl2 = 0;
        #pragma unroll
        for (int u = 0; u < 32; ++u) nl2 += (keysr[u] < Tx) ? 1u : 0u;
        unsigned sc2 = nl2;
        #pragma unroll
        for (int s = 1; s < 64; s <<= 1) {
            unsigned t2 = __shfl_up(sc2, s);
            if (lane >= s) sc2 += t2;
        }
        unsigned cstrict = __shfl(sc2, 63);
        unsigned o = sc2 - nl2;
        #pragma unroll
        for (int u = 0; u < 32; ++u) {
            if (keysr[u] < Tx) { op[o] = bofs + u * 64 + lane; ++o; }
        }
        int rem = KK - (int)cstrict;
        int ebase = (int)cstrict;
        #pragma unroll
        for (int u = 0; u < 32; ++u) {
            if (rem > 0) {
                bool eq = (keysr[u] == Tx);
                unsigned long long bm = __ballot(eq);
                int before = __popcll(bm & ((1ull << lane) - 1ull));
                if (eq && before < rem) op[ebase + before] = bofs + u * 64 + lane;
                int take = __popcll(bm);
                if (take > rem) take = rem;
                ebase += take;
                rem -= take;
            }
        }
    }
}

// ---------------- Wt[c][j] build: [Wd | Wtail] transposed, zero-padded ----------------
__global__ __launch_bounds__(256) void wt_build_kernel(const float* __restrict__ W,
                                                       float* __restrict__ Wt,
                                                       int D, int Dp, int C) {
    int i = blockIdx.x * 256 + threadIdx.x;
    if (i < 2 * C * Dp) {
        int c = i / Dp, j = i % Dp;
        float v = 0.f;
        if (j < D) {
            v = (c < C) ? (W[j * C + c] - W[(D + j) * C + c])
                        : W[(D + j) * C + (c - C)];
        }
        Wt[i] = v;
    }
}

// ---------------- X[TOT,Dp] @ Wt^T -> basexw[TOT,2C] ----------------
template <int NJ4, int C2>
__global__ __launch_bounds__(256) void xw_gemm_kernel(const float* __restrict__ x, int ldx,
                                                      const float* __restrict__ Wt,
                                                      float* __restrict__ bx) {
    constexpr int PG = 256 / C2;   // point groups
    constexpr int PTS = 16 / PG;   // points per thread
    __shared__ float4 Xs[16][NJ4];
    const int tid = threadIdx.x;
    const int p0 = blockIdx.x * 16;
    for (int i = tid; i < 16 * NJ4; i += 256) {
        int r = i / NJ4, j4 = i % NJ4;
        Xs[r][j4] = *reinterpret_cast<const float4*>(x + (size_t)(p0 + r) * ldx + j4 * 4);
    }
    __syncthreads();
    const int c = tid % C2, pg = tid / C2;
    const float4* wrow = reinterpret_cast<const float4*>(Wt + (size_t)c * (NJ4 * 4));
    float acc[PTS];
    #pragma unroll
    for (int u = 0; u < PTS; ++u) acc[u] = 0.f;
    #pragma unroll
    for (int j4 = 0; j4 < NJ4; ++j4) {
        float4 w4 = wrow[j4];
        #pragma unroll
        for (int u = 0; u < PTS; ++u) {
            float4 x4 = Xs[pg * PTS + u][j4];
            acc[u] += x4.x * w4.x + x4.y * w4.y + x4.z * w4.z + x4.w * w4.w;
        }
    }
    #pragma unroll
    for (int u = 0; u < PTS; ++u)
        bx[(size_t)(p0 + pg * PTS + u) * C2 + c] = acc[u];
}

// ---------------- edge pass: gather XW, stats + per-point max/min ----------------
template <int C>
__global__ __launch_bounds__(256) void edge_pass_kernel(const float* __restrict__ bx,
                                                        const int* __restrict__ idx,
                                                        float* __restrict__ psum,
                                                        float* __restrict__ psum2,
                                                        float* __restrict__ mmax,
                                                        float* __restrict__ mmin) {
    constexpr int PT = 256 / C;
    constexpr int C2 = 2 * C;
    __shared__ int sidx[PT][KK];
    __shared__ float red[256];
    const int tid = threadIdx.x;
    const int c = tid % C;
    const int pl = tid / C;
    float s1 = 0.f, s2 = 0.f;
    const int NT = TOT / PT;
    for (int t = blockIdx.x; t < NT; t += EBLK) {
        const int p0 = t * PT;
        __syncthreads();
        if (tid < PT * KK) sidx[tid / KK][tid % KK] = idx[(size_t)p0 * KK + tid];
        __syncthreads();
        const int p = p0 + pl;
        const float bv = bx[(size_t)p * C2 + c];
        float A = 0.f, Q = 0.f, M = -FLT_MAX, mn = FLT_MAX;
        #pragma unroll
        for (int k = 0; k < KK; ++k) {
            float v = bx[(size_t)sidx[pl][k] * C2 + C + c];
            A += v; Q += v * v; M = fmaxf(M, v); mn = fminf(mn, v);
        }
        s1 += (float)KK * bv + A;
        s2 += (float)KK * bv * bv + 2.f * bv * A + Q;
        mmax[(size_t)p * C + c] = bv + M;
        mmin[(size_t)p * C + c] = bv + mn;
    }
    red[tid] = s1;
    __syncthreads();
    if (tid < C) {
        float v = red[tid];
        #pragma unroll
        for (int u = 1; u < PT; ++u) v += red[tid + u * C];
        psum[(size_t)blockIdx.x * C + tid] = v;
    }
    __syncthreads();
    red[tid] = s2;
    __syncthreads();
    if (tid < C) {
        float v = red[tid];
        #pragma unroll
        for (int u = 1; u < PT; ++u) v += red[tid + u * C];
        psum2[(size_t)blockIdx.x * C + tid] = v;
    }
}

// ---------------- BN stats reduce -> alpha/beta ----------------
__global__ __launch_bounds__(256) void bn_reduce_kernel(
        const float* __restrict__ psum, const float* __restrict__ psum2,
        int npart, int C, const float* __restrict__ g, const float* __restrict__ bb,
        float inv_cnt, float* __restrict__ alpha, float* __restrict__ beta) {
    const int c = blockIdx.x;
    const int tid = threadIdx.x;
    __shared__ float r1[256], r2[256];
    float s1 = 0.f, s2 = 0.f;
    for (int i = tid; i < npart; i += 256) {
        s1 += psum[(size_t)i * C + c];
        s2 += psum2[(size_t)i * C + c];
    }
    r1[tid] = s1; r2[tid] = s2;
    __syncthreads();
    for (int s = 128; s > 0; s >>= 1) {
        if (tid < s) { r1[tid] += r1[tid + s]; r2[tid] += r2[tid + s]; }
        __syncthreads();
    }
    if (tid == 0) {
        float mean = r1[0] * inv_cnt;
        float var = r2[0] * inv_cnt - mean * mean;
        float a = g[c] * rsqrtf(var + 1e-5f);
        alpha[c] = a;
        beta[c] = bb[c] - mean * a;
    }
}

// ---------------- edge finalize: pick by sign(alpha), affine+leaky; f32 + bf16 hi/lo (+sq) ----------------
template <int C>
__global__ __launch_bounds__(256) void edge_finalize_kernel(const float* __restrict__ mmax,
                                                            const float* __restrict__ mmin,
                                                            const float* __restrict__ alpha,
                                                            const float* __restrict__ beta,
                                                            float* __restrict__ xcf, int ldf,
                                                            unsigned short* __restrict__ xch,
                                                            unsigned short* __restrict__ xcl,
                                                            int ch_off,
                                                            float* __restrict__ sq_out) {
    constexpr int CQ = C / 4;
    __shared__ float red[256];
    const int tid = threadIdx.x;
    int i4 = blockIdx.x * 256 + tid;
    float4 o = make_float4(0.f, 0.f, 0.f, 0.f);
    int p = 0;
    if (i4 < TOT * CQ) {
        int cq; p = i4 / CQ; cq = i4 - p * CQ;
        float4 M4 = reinterpret_cast<const float4*>(mmax)[i4];
        float4 m4 = reinterpret_cast<const float4*>(mmin)[i4];
        float4 a4 = reinterpret_cast<const float4*>(alpha)[cq];
        float4 b4 = reinterpret_cast<const float4*>(beta)[cq];
        o.x = leaky(a4.x * (a4.x >= 0.f ? M4.x : m4.x) + b4.x);
        o.y = leaky(a4.y * (a4.y >= 0.f ? M4.y : m4.y) + b4.y);
        o.z = leaky(a4.z * (a4.z >= 0.f ? M4.z : m4.z) + b4.z);
        o.w = leaky(a4.w * (a4.w >= 0.f ? M4.w : m4.w) + b4.w);
        if (xcf)
            *reinterpret_cast<float4*>(xcf + (size_t)p * ldf + cq * 4) = o;
        ushort4 hh, ll;
        hh.x = bf16_rne(o.x); ll.x = bf16_rne(o.x - bf16_f(hh.x));
        hh.y = bf16_rne(o.y); ll.y = bf16_rne(o.y - bf16_f(hh.y));
        hh.z = bf16_rne(o.z); ll.z = bf16_rne(o.z - bf16_f(hh.z));
        hh.w = bf16_rne(o.w); ll.w = bf16_rne(o.w - bf16_f(hh.w));
        const size_t oo = (size_t)p * 256 + ch_off + cq * 4;
        *reinterpret_cast<ushort4*>(xch + oo) = hh;
        *reinterpret_cast<ushort4*>(xcl + oo) = ll;
    }
    if (sq_out) {   // only used for C=64 (CQ=16, 16 pts/block, exact grid)
        red[tid] = o.x * o.x + o.y * o.y + o.z * o.z + o.w * o.w;
        __syncthreads();
        if ((tid & (CQ - 1)) == 0) {
            float s = red[tid];
            #pragma unroll
            for (int u = 1; u < CQ; ++u) s += red[tid + u];
            sq_out[p] = s;
        }
    }
}

// ---------------- Wf -> bf16 hi/lo, transposed to [1024][256] ----------------
__global__ __launch_bounds__(256) void wfhl_build_kernel(const float* __restrict__ Wf,
                                                         unsigned short* __restrict__ wfh,
                                                         unsigned short* __restrict__ wfl) {
    int i = blockIdx.x * 256 + threadIdx.x;
    if (i < 256 * 1024) {
        int e = i / 1024, o = i - e * 1024;
        float v = Wf[i];
        unsigned short h = bf16_rne(v);
        wfh[(size_t)o * 256 + e] = h;
        wfl[(size_t)o * 256 + e] = bf16_rne(v - bf16_f(h));
    }
}

// ---------------- conv_final via MFMA bf16x3 + stat partials ----------------
__global__ __launch_bounds__(256) void fc_mfma_kernel(const unsigned short* __restrict__ xch,
                                                      const unsigned short* __restrict__ xcl,
                                                      const unsigned short* __restrict__ wfh,
                                                      const unsigned short* __restrict__ wfl,
                                                      float* __restrict__ psum,
                                                      float* __restrict__ psum2,
                                                      float* __restrict__ pmax,
                                                      float* __restrict__ pmin) {
    __shared__ __align__(16) unsigned short Ah[128 * 64];
    __shared__ __align__(16) unsigned short Al[128 * 64];
    __shared__ __align__(16) unsigned short Bh[128 * 64];
    __shared__ __align__(16) unsigned short Bl[128 * 64];
    const int tid = threadIdx.x;
    const int w = tid >> 6, lane = tid & 63;
    const int wr = w >> 1, wc = w & 1;
    const int pt = blockIdx.x, ct = blockIdx.y;
    f32x16 acc00 = {}, acc01 = {}, acc10 = {}, acc11 = {};
    for (int kc = 0; kc < 4; ++kc) {
        const int k0 = kc * 64;
        __syncthreads();
        for (int i = tid; i < 1024; i += 256) {
            const int r = i >> 3, slot = i & 7;
            const int ls = r * 64 + ((slot ^ (r & 7)) << 3);
            const size_t ga = (size_t)(pt * 128 + r) * 256 + k0 + slot * 8;
            const size_t gb = (size_t)(ct * 128 + r) * 256 + k0 + slot * 8;
            *reinterpret_cast<uint4*>(&Ah[ls]) = *reinterpret_cast<const uint4*>(&xch[ga]);
            *reinterpret_cast<uint4*>(&Al[ls]) = *reinterpret_cast<const uint4*>(&xcl[ga]);
            *reinterpret_cast<uint4*>(&Bh[ls]) = *reinterpret_cast<const uint4*>(&wfh[gb]);
            *reinterpret_cast<uint4*>(&Bl[ls]) = *reinterpret_cast<const uint4*>(&wfl[gb]);
        }
        __syncthreads();
        const int h = lane >> 5;
        const int ar0 = wr * 64 + (lane & 31), ar1 = ar0 + 32;
        const int bc0 = wc * 64 + (lane & 31), bc1 = bc0 + 32;
        #pragma unroll
        for (int s = 0; s < 4; ++s) {
            const int sl = s * 2 + h;
            const int ia0 = ar0 * 64 + ((sl ^ (ar0 & 7)) << 3);
            const int ia1 = ar1 * 64 + ((sl ^ (ar1 & 7)) << 3);
            const int ib0 = bc0 * 64 + ((sl ^ (bc0 & 7)) << 3);
            const int ib1 = bc1 * 64 + ((sl ^ (bc1 & 7)) << 3);
            short8v a0h = *reinterpret_cast<const short8v*>(&Ah[ia0]);
            short8v a1h = *reinterpret_cast<const short8v*>(&Ah[ia1]);
            short8v a0l = *reinterpret_cast<const short8v*>(&Al[ia0]);
            short8v a1l = *reinterpret_cast<const short8v*>(&Al[ia1]);
            short8v b0h = *reinterpret_cast<const short8v*>(&Bh[ib0]);
            short8v b1h = *reinterpret_cast<const short8v*>(&Bh[ib1]);
            short8v b0l = *reinterpret_cast<const short8v*>(&Bl[ib0]);
            short8v b1l = *reinterpret_cast<const short8v*>(&Bl[ib1]);
            acc00 = __builtin_amdgcn_mfma_f32_32x32x16_bf16(a0h, b0h, acc00, 0, 0, 0);
            acc01 = __builtin_amdgcn_mfma_f32_32x32x16_bf16(a0h, b1h, acc01, 0, 0, 0);
            acc10 = __builtin_amdgcn_mfma_f32_32x32x16_bf16(a1h, b0h, acc10, 0, 0, 0);
            acc11 = __builtin_amdgcn_mfma_f32_32x32x16_bf16(a1h, b1h, acc11, 0, 0, 0);
            acc00 = __builtin_amdgcn_mfma_f32_32x32x16_bf16(a0h, b0l, acc00, 0, 0, 0);
            acc01 = __builtin_amdgcn_mfma_f32_32x32x16_bf16(a0h, b1l, acc01, 0, 0, 0);
            acc10 = __builtin_amdgcn_mfma_f32_32x32x16_bf16(a1h, b0l, acc10, 0, 0, 0);
            acc11 = __builtin_amdgcn_mfma_f32_32x32x16_bf16(a1h, b1l, acc11, 0, 0, 0);
            acc00 = __builtin_amdgcn_mfma_f32_32x32x16_bf16(a0l, b0h, acc00, 0, 0, 0);
            acc01 = __builtin_amdgcn_mfma_f32_32x32x16_bf16(a0l, b1h, acc01, 0, 0, 0);
            acc10 = __builtin_amdgcn_mfma_f32_32x32x16_bf16(a1l, b0h, acc10, 0, 0, 0);
            acc11 = __builtin_amdgcn_mfma_f32_32x32x16_bf16(a1l, b1h, acc11, 0, 0, 0);
        }
    }
    float* red = reinterpret_cast<float*>(Ah);   // [2 wr][128 ch][4 stats]
    __syncthreads();
    #pragma unroll
    for (int fc = 0; fc < 2; ++fc) {
        float s1 = 0.f, s2 = 0.f, mx = -FLT_MAX, mn = FLT_MAX;
        #pragma unroll
        for (int e = 0; e < 16; ++e) {
            float v0 = (fc == 0) ? acc00[e] : acc01[e];
            float v1 = (fc == 0) ? acc10[e] : acc11[e];
            s1 += v0 + v1;
            s2 += v0 * v0 + v1 * v1;
            mx = fmaxf(mx, fmaxf(v0, v1));
            mn = fminf(mn, fminf(v0, v1));
        }
        s1 += __shfl_xor(s1, 32);
        s2 += __shfl_xor(s2, 32);
        mx = fmaxf(mx, __shfl_xor(mx, 32));
        mn = fminf(mn, __shfl_xor(mn, 32));
        if (lane < 32) {
            const int ch = wc * 64 + fc * 32 + lane;
            float4 st; st.x = s1; st.y = s2; st.z = mx; st.w = mn;
            *reinterpret_cast<float4*>(&red[(wr * 128 + ch) * 4]) = st;
        }
    }
    __syncthreads();
    if (tid < 128) {
        float4 s0 = *reinterpret_cast<const float4*>(&red[tid * 4]);
        float4 s1 = *reinterpret_cast<const float4*>(&red[(128 + tid) * 4]);
        const size_t go = (size_t)pt * 1024 + ct * 128 + tid;
        psum[go]  = s0.x + s1.x;
        psum2[go] = s0.y + s1.y;
        pmax[go]  = fmaxf(s0.z, s1.z);
        pmin[go]  = fminf(s0.w, s1.w);
    }
}

// ---------------- gfeat finalize (16 point-tile partials per batch) ----------------
__global__ __launch_bounds__(256) void gfeat_final_kernel(const float* __restrict__ pmax,
                                                          const float* __restrict__ pmin,
                                                          const float* __restrict__ alpha,
                                                          const float* __restrict__ beta,
                                                          float* __restrict__ gfeat) {
    int i = blockIdx.x * 256 + threadIdx.x;
    if (i < NB * 1024) {
        int b = i >> 10, c = i & 1023;
        float mx = -FLT_MAX, mn = FLT_MAX;
        for (int j = 0; j < 16; ++j) {
            size_t o = (size_t)(b * 16 + j) * 1024 + c;
            mx = fmaxf(mx, pmax[o]);
            mn = fminf(mn, pmin[o]);
        }
        float a = alpha[c];
        gfeat[i] = leaky(a * (a >= 0.f ? mx : mn) + beta[c]);
    }
}

// ---------------- classifier: split-K skinny GEMM, A is [16][K] ----------------
template <int CHUNK>
__global__ __launch_bounds__(256) void skinny_gemm_kernel(const float* __restrict__ A,
                                                          const float* __restrict__ W,
                                                          float* __restrict__ part,
                                                          int K, int N) {
    __shared__ float Asub[4][16][CHUNK];
    const int tid = threadIdx.x;
    const int g = tid >> 6, lane = tid & 63;
    const int c = blockIdx.x * 64 + lane;
    const int ks = blockIdx.y * 4 + g;
    const int e0 = ks * CHUNK;
    for (int i = lane; i < 16 * CHUNK; i += 64) {
        const int m = i / CHUNK, el = i - m * CHUNK;
        Asub[g][m][el] = A[(size_t)m * K + e0 + el];
    }
    if (c < N) {
        float acc[16];
        #pragma unroll
        for (int m = 0; m < 16; ++m) acc[m] = 0.f;
        #pragma unroll 4
        for (int el = 0; el < CHUNK; ++el) {
            float w = W[(size_t)(e0 + el) * N + c];
            #pragma unroll
            for (int m = 0; m < 16; ++m) acc[m] += Asub[g][m][el] * w;
        }
        #pragma unroll
        for (int m = 0; m < 16; ++m)
            part[((size_t)ks * 16 + m) * N + c] = acc[m];
    }
}

// ---------------- classifier finish: reduce splits + bias (+BN over rows + leaky) ----------------
__global__ __launch_bounds__(256) void fin_kernel(const float* __restrict__ part,
                                                  int S, int N,
                                                  const float* __restrict__ bias,
                                                  const float* __restrict__ g,
                                                  const float* __restrict__ bb,
                                                  int do_bn,
                                                  float* __restrict__ out, int Nout) {
    int c = blockIdx.x * 256 + threadIdx.x;
    if (c >= N) return;
    float z[16];
    #pragma unroll
    for (int m = 0; m < 16; ++m) z[m] = bias[c];
    for (int s = 0; s < S; ++s)
        #pragma unroll
        for (int m = 0; m < 16; ++m) z[m] += part[((size_t)s * 16 + m) * N + c];
    if (do_bn) {
        float s1 = 0.f, s2 = 0.f;
        #pragma unroll
        for (int m = 0; m < 16; ++m) { s1 += z[m]; s2 += z[m] * z[m]; }
        float mean = s1 * (1.f / 16.f);
        float var = s2 * (1.f / 16.f) - mean * mean;
        float a = g[c] * rsqrtf(var + 1e-5f);
        float be = bb[c] - mean * a;
        #pragma unroll
        for (int m = 0; m < 16; ++m) out[(size_t)m * N + c] = leaky(a * z[m] + be);
    } else {
        if (c < Nout)
            #pragma unroll
            for (int m = 0; m < 16; ++m) out[(size_t)m * Nout + c] = z[m];
    }
}

static void run_knn_feat(const unsigned short* xh, const unsigned short* xl, int ch_off,
                         const float* xf, const float* sq, unsigned short* keys16, int CB,
                         int* idx, hipStream_t stream) {
    for (int b0 = 0; b0 < NB; b0 += CB) {
        dim3 g(256, CB);   // full tile grid
        dist_mfma16_kernel<<<g, 256, 0, stream>>>(xh, xl, ch_off, sq, b0, keys16);
        knn_sr_kernel<64><<<CB * NP / 4, 256, 0, stream>>>(keys16, b0, xf, 128, sq, idx);
    }
}

} // namespace

extern "C" void kernel_launch(void* const* d_in, const int* in_sizes, int n_in,
                              void* d_out, int out_size, void* d_ws, size_t ws_size,
                              hipStream_t stream) {
    (void)in_sizes; (void)n_in; (void)out_size;
    const float* pos = (const float*)d_in[0];
    const float* W1  = (const float*)d_in[1];
    const float* g1  = (const float*)d_in[2];
    const float* b1  = (const float*)d_in[3];
    const float* W2  = (const float*)d_in[4];
    const float* g2  = (const float*)d_in[5];
    const float* b2  = (const float*)d_in[6];
    const float* W3  = (const float*)d_in[7];
    const float* g3  = (const float*)d_in[8];
    const float* b3  = (const float*)d_in[9];
    const float* Wf  = (const float*)d_in[10];
    const float* gf  = (const float*)d_in[11];
    const float* bf  = (const float*)d_in[12];
    const float* W4  = (const float*)d_in[13];
    const float* b4  = (const float*)d_in[14];
    const float* g4  = (const float*)d_in[15];
    const float* be4 = (const float*)d_in[16];
    const float* W5  = (const float*)d_in[17];
    const float* b5  = (const float*)d_in[18];
    const float* g5  = (const float*)d_in[19];
    const float* be5 = (const float*)d_in[20];
    const float* W6  = (const float*)d_in[21];
    const float* b6  = (const float*)d_in[22];
    float* out = (float*)d_out;

    float* ws = (float*)d_ws;
    size_t off = 0;
    int*   idx    = (int*)ws;      off += (size_t)TOT * KK;          // 2.6 MB
    float* pos4   = ws + off;      off += (size_t)TOT * 4;
    float* sq     = ws + off;      off += (size_t)TOT;
    float* Wt     = ws + off;      off += 256 * 64;
    float* basexw = ws + off;      off += (size_t)TOT * 256;         // 32 MB
    float* mmax   = ws + off;      off += (size_t)TOT * 128;         // 16 MB
    float* mmin   = ws + off;      off += (size_t)TOT * 128;         // 16 MB
    float* xc12   = ws + off;      off += (size_t)TOT * 128;         // 16 MB (x1|x2 f32)
    unsigned short* xch = (unsigned short*)(ws + off); off += (size_t)TOT * 128;  // 16 MB bf16 hi
    unsigned short* xcl = (unsigned short*)(ws + off); off += (size_t)TOT * 128;  // 16 MB bf16 lo
    unsigned short* wfh = (unsigned short*)(ws + off); off += (size_t)1024 * 128;
    unsigned short* wfl = (unsigned short*)(ws + off); off += (size_t)1024 * 128;
    float* psum   = ws + off;      off += (size_t)512 * 1024;        // 2 MB
    float* psum2  = ws + off;      off += (size_t)512 * 1024;
    float* pmax   = ws + off;      off += (size_t)512 * 1024;
    float* pmin   = ws + off;      off += (size_t)512 * 1024;
    float* alpha  = ws + off;      off += 1024;
    float* beta   = ws + off;      off += 1024;
    float* gfeat  = ws + off;      off += NB * 1024;
    float* part   = ws + off;      off += 8 * 16 * 512;              // split-K partials
    float* h4     = ws + off;      off += NB * 512;
    float* h5     = ws + off;      off += NB * 256;
    unsigned short* keys16 = (unsigned short*)(ws + off);
    const size_t avail = (ws_size > off * 4) ? (ws_size - off * 4) : 0;
    const size_t per_batch = (size_t)NP * NP * 2;   // 16-bit keys
    int CB = 1;
    for (int cb : {8, 4, 2}) {     // keys16 <= 64 MB, L3-resident
        if ((size_t)cb * per_batch <= avail) { CB = cb; break; }
    }

    const int npts_blk = (TOT + 255) / 256;

    // ---------- Layer 1 (D=3 padded to 4, C=64) ----------
    pos4sq_kernel<<<npts_blk, 256, 0, stream>>>(pos, pos4, sq);
    knn_l1_fused_kernel<<<TOT / 16, 256, 0, stream>>>(pos4, sq, idx);
    wt_build_kernel<<<2, 256, 0, stream>>>(W1, Wt, 3, 4, 64);
    xw_gemm_kernel<1, 128><<<TOT / 16, 256, 0, stream>>>(pos4, 4, Wt, basexw);
    edge_pass_kernel<64><<<EBLK, 256, 0, stream>>>(basexw, idx, psum, psum2, mmax, mmin);
    bn_reduce_kernel<<<64, 256, 0, stream>>>(psum, psum2, EBLK, 64, g1, b1,
                                             1.f / (float)(TOT * KK), alpha, beta);
    edge_finalize_kernel<64><<<TOT * 16 / 256, 256, 0, stream>>>(
        mmax, mmin, alpha, beta, xc12 + 0, 128, xch, xcl, 0, sq);   // sq for layer 2

    // ---------- Layer 2 (D=64, C=64), input x1 = xc12[:,0:64] / xch[:,0:64] ----------
    run_knn_feat(xch, xcl, 0, xc12 + 0, sq, keys16, CB, idx, stream);
    wt_build_kernel<<<32, 256, 0, stream>>>(W2, Wt, 64, 64, 64);
    xw_gemm_kernel<16, 128><<<TOT / 16, 256, 0, stream>>>(xc12 + 0, 128, Wt, basexw);
    edge_pass_kernel<64><<<EBLK, 256, 0, stream>>>(basexw, idx, psum, psum2, mmax, mmin);
    bn_reduce_kernel<<<64, 256, 0, stream>>>(psum, psum2, EBLK, 64, g2, b2,
                                             1.f / (float)(TOT * KK), alpha, beta);
    edge_finalize_kernel<64><<<TOT * 16 / 256, 256, 0, stream>>>(
        mmax, mmin, alpha, beta, xc12 + 64, 128, xch, xcl, 64, sq); // sq for layer 3

    // ---------- Layer 3 (D=64, C=128), input x2 = xc12[:,64:128] / xch[:,64:128] ----------
    run_knn_feat(xch, xcl, 64, xc12 + 64, sq, keys16, CB, idx, stream);
    wt_build_kernel<<<64, 256, 0, stream>>>(W3, Wt, 64, 64, 128);
    xw_gemm_kernel<16, 256><<<TOT / 16, 256, 0, stream>>>(xc12 + 64, 128, Wt, basexw);
    edge_pass_kernel<128><<<EBLK, 256, 0, stream>>>(basexw, idx, psum, psum2, mmax, mmin);
    bn_reduce_kernel<<<128, 256, 0, stream>>>(psum, psum2, EBLK, 128, g3, b3,
                                              1.f / (float)(TOT * KK), alpha, beta);
    edge_finalize_kernel<128><<<TOT * 32 / 256, 256, 0, stream>>>(
        mmax, mmin, alpha, beta, nullptr, 0, xch, xcl, 128, nullptr);

    // ---------- conv_final (MFMA bf16x3) + global max pool ----------
    wfhl_build_kernel<<<1024, 256, 0, stream>>>(Wf, wfh, wfl);
    {
        dim3 g(TOT / 128, 8, 1);
        fc_mfma_kernel<<<g, 256, 0, stream>>>(xch, xcl, wfh, wfl, psum, psum2, pmax, pmin);
    }
    bn_reduce_kernel<<<1024, 256, 0, stream>>>(psum, psum2, 256, 1024, gf, bf,
                                               1.f / (float)TOT, alpha, beta);
    gfeat_final_kernel<<<64, 256, 0, stream>>>(pmax, pmin, alpha, beta, gfeat);

    // ---------- classifier (split-K skinny GEMMs) ----------
    skinny_gemm_kernel<128><<<dim3(8, 2), 256, 0, stream>>>(gfeat, W4, part, 1024, 512);
    fin_kernel<<<2, 256, 0, stream>>>(part, 8, 512, b4, g4, be4, 1, h4, 512);
    skinny_gemm_kernel<64><<<dim3(4, 2), 256, 0, stream>>>(h4, W5, part, 512, 256);
    fin_kernel<<<1, 256, 0, stream>>>(part, 8, 256, b5, g5, be5, 1, h5, 256);
    skinny_gemm_kernel<32><<<dim3(1, 2), 256, 0, stream>>>(h5, W6, part, 256, 40);
    fin_kernel<<<1, 256, 0, stream>>>(part, 8, 40, b6, nullptr, nullptr, 0, out, 40);
}

// Round 15
// 740.162 us; speedup vs baseline: 1.1604x; 1.1604x over previous
//
#include <hip/hip_runtime.h>
#include <float.h>
#include <math.h>

namespace {

constexpr int NB = 16;
constexpr int NP = 2048;
constexpr int KK = 20;
constexpr int TOT = NB * NP;   // 32768
constexpr int EBLK = 1024;     // edge pass grid

typedef short short8v __attribute__((ext_vector_type(8)));   // 8 bf16 (4 VGPRs)
typedef float f32x16 __attribute__((ext_vector_type(16)));

__device__ __forceinline__ float leaky(float v) { return fmaxf(v, 0.2f * v); }

__device__ __forceinline__ unsigned short bf16_rne(float x) {
    unsigned u = __float_as_uint(x);
    unsigned r = u + 0x7FFFu + ((u >> 16) & 1u);
    return (unsigned short)(r >> 16);
}
__device__ __forceinline__ float bf16_f(unsigned short h) {
    return __uint_as_float(((unsigned)h) << 16);
}
__device__ __forceinline__ unsigned mono_key(float d) {
    unsigned bits = __float_as_uint(d);
    return (bits & 0x80000000u) ? ~bits : (bits | 0x80000000u);
}
__device__ __forceinline__ unsigned short key16(float d) {
    return (unsigned short)(mono_key(d) >> 16);
}

// ---------------- pos -> pos4 (pad to 4) + squared norm ----------------
__global__ __launch_bounds__(256) void pos4sq_kernel(const float* __restrict__ pos,
                                                     float* __restrict__ pos4,
                                                     float* __restrict__ sq) {
    int i = blockIdx.x * 256 + threadIdx.x;
    if (i < TOT) {
        float x = pos[i * 3 + 0], y = pos[i * 3 + 1], z = pos[i * 3 + 2];
        pos4[i * 4 + 0] = x;
        pos4[i * 4 + 1] = y;
        pos4[i * 4 + 2] = z;
        pos4[i * 4 + 3] = 0.f;
        sq[i] = x * x + y * y + z * z;
    }
}

// ---------------- layer-1 exact f32 symmetric distance -> 16-bit keys ----------------
template <int KTOT>
__global__ __launch_bounds__(256) void dist_sym16_kernel(const float* __restrict__ x, int ldx,
                                                         const float* __restrict__ sq,
                                                         int b0,
                                                         unsigned short* __restrict__ keys) {
    constexpr int KC = (KTOT < 32) ? KTOT : 32;
    constexpr int F4 = KC / 4;
    __shared__ float Ak[KC][128];
    __shared__ float Bk[KC][128];
    const int tid = threadIdx.x;
    const int tr = tid >> 4, tc = tid & 15;
    int tm = (int)((sqrtf(8.f * blockIdx.x + 1.f) - 1.f) * 0.5f);
    while ((tm + 1) * (tm + 2) / 2 <= (int)blockIdx.x) ++tm;
    while (tm * (tm + 1) / 2 > (int)blockIdx.x) --tm;
    const int tn = blockIdx.x - tm * (tm + 1) / 2;
    const int m0 = tm * 128, n0 = tn * 128;
    const int bofs = (b0 + blockIdx.y) * NP;
    const float* xb = x + (size_t)bofs * ldx;
    float acc[8][8] = {};
    for (int k0 = 0; k0 < KTOT; k0 += KC) {
        __syncthreads();
        for (int i = tid; i < 128 * F4; i += 256) {
            const int r = i / F4, c4 = i % F4;
            const int rs = r ^ ((c4 & 3) << 3);
            float4 v = *reinterpret_cast<const float4*>(xb + (size_t)(m0 + r) * ldx + k0 + c4 * 4);
            Ak[c4 * 4 + 0][rs] = v.x; Ak[c4 * 4 + 1][rs] = v.y;
            Ak[c4 * 4 + 2][rs] = v.z; Ak[c4 * 4 + 3][rs] = v.w;
        }
        for (int i = tid; i < 128 * F4; i += 256) {
            const int r = i / F4, c4 = i % F4;
            const int rs = r ^ ((c4 & 3) << 3);
            float4 v = *reinterpret_cast<const float4*>(xb + (size_t)(n0 + r) * ldx + k0 + c4 * 4);
            Bk[c4 * 4 + 0][rs] = v.x; Bk[c4 * 4 + 1][rs] = v.y;
            Bk[c4 * 4 + 2][rs] = v.z; Bk[c4 * 4 + 3][rs] = v.w;
        }
        __syncthreads();
        #pragma unroll
        for (int k = 0; k < KC; ++k) {
            const int sw = ((k >> 2) & 3) << 3;
            const int ia = (tr * 4) ^ sw;
            const int ib = (tc * 4) ^ sw;
            float4 al = *reinterpret_cast<const float4*>(&Ak[k][ia]);
            float4 ah = *reinterpret_cast<const float4*>(&Ak[k][64 + ia]);
            float4 bl = *reinterpret_cast<const float4*>(&Bk[k][ib]);
            float4 bh = *reinterpret_cast<const float4*>(&Bk[k][64 + ib]);
            float a[8] = {al.x, al.y, al.z, al.w, ah.x, ah.y, ah.z, ah.w};
            float bv[8] = {bl.x, bl.y, bl.z, bl.w, bh.x, bh.y, bh.z, bh.w};
            #pragma unroll
            for (int i = 0; i < 8; ++i)
                #pragma unroll
                for (int j = 0; j < 8; ++j)
                    acc[i][j] += a[i] * bv[j];
        }
    }
    float sa[8], sb[8];
    #pragma unroll
    for (int i = 0; i < 8; ++i) sa[i] = sq[bofs + m0 + ((i < 4) ? tr * 4 + i : 64 + tr * 4 + i - 4)];
    #pragma unroll
    for (int j = 0; j < 8; ++j) sb[j] = sq[bofs + n0 + ((j < 4) ? tc * 4 + j : 64 + tc * 4 + j - 4)];
    #pragma unroll
    for (int i = 0; i < 8; ++i) {
        const int row = (i < 4) ? tr * 4 + i : 64 + tr * 4 + i - 4;
        unsigned short* kr = keys + ((size_t)blockIdx.y * NP + m0 + row) * NP + n0;
        unsigned short kk[8];
        #pragma unroll
        for (int j = 0; j < 8; ++j) kk[j] = key16(sa[i] + sb[j] - 2.f * acc[i][j]);
        *reinterpret_cast<ushort4*>(kr + tc * 4) = make_ushort4(kk[0], kk[1], kk[2], kk[3]);
        *reinterpret_cast<ushort4*>(kr + 64 + tc * 4) = make_ushort4(kk[4], kk[5], kk[6], kk[7]);
    }
    if (tm != tn) {
        #pragma unroll
        for (int j = 0; j < 8; ++j) {
            const int col = (j < 4) ? tc * 4 + j : 64 + tc * 4 + j - 4;
            unsigned short* mr = keys + ((size_t)blockIdx.y * NP + n0 + col) * NP + m0;
            unsigned short lo4[4], hi4[4];
            #pragma unroll
            for (int i = 0; i < 4; ++i) {
                lo4[i] = key16(sa[i] + sb[j] - 2.f * acc[i][j]);
                hi4[i] = key16(sa[i + 4] + sb[j] - 2.f * acc[i + 4][j]);
            }
            *reinterpret_cast<ushort4*>(mr + tr * 4) = make_ushort4(lo4[0], lo4[1], lo4[2], lo4[3]);
            *reinterpret_cast<ushort4*>(mr + 64 + tr * 4) = make_ushort4(hi4[0], hi4[1], hi4[2], hi4[3]);
        }
    }
}

// ---------------- layers 2/3: MFMA bf16x3 distance -> 16-bit keys (transposed store) ----------------
__global__ __launch_bounds__(256) void dist_mfma16_kernel(const unsigned short* __restrict__ xh,
                                                          const unsigned short* __restrict__ xl,
                                                          int ch_off,
                                                          const float* __restrict__ sq,
                                                          int b0,
                                                          unsigned short* __restrict__ keys) {
    __shared__ __align__(16) unsigned short Ah[128 * 64];
    __shared__ __align__(16) unsigned short Al[128 * 64];
    __shared__ __align__(16) unsigned short Bh[128 * 64];
    __shared__ __align__(16) unsigned short Bl[128 * 64];
    const int tid = threadIdx.x;
    const int w = tid >> 6, lane = tid & 63;
    const int wr = w >> 1, wc = w & 1;
    const int tm = blockIdx.x >> 4, tn = blockIdx.x & 15;
    const int m0 = tm * 128, n0 = tn * 128;
    const int bofs = (b0 + blockIdx.y) * NP;
    for (int i = tid; i < 1024; i += 256) {
        const int r = i >> 3, slot = i & 7;
        const int ls = r * 64 + ((slot ^ (r & 7)) << 3);
        const size_t ga = (size_t)(bofs + m0 + r) * 256 + ch_off + slot * 8;
        const size_t gb = (size_t)(bofs + n0 + r) * 256 + ch_off + slot * 8;
        *reinterpret_cast<uint4*>(&Ah[ls]) = *reinterpret_cast<const uint4*>(&xh[ga]);
        *reinterpret_cast<uint4*>(&Al[ls]) = *reinterpret_cast<const uint4*>(&xl[ga]);
        *reinterpret_cast<uint4*>(&Bh[ls]) = *reinterpret_cast<const uint4*>(&xh[gb]);
        *reinterpret_cast<uint4*>(&Bl[ls]) = *reinterpret_cast<const uint4*>(&xl[gb]);
    }
    __syncthreads();
    const int h = lane >> 5;
    const int ar0 = wr * 64 + (lane & 31), ar1 = ar0 + 32;
    const int bc0 = wc * 64 + (lane & 31), bc1 = bc0 + 32;
    f32x16 acc00 = {}, acc01 = {}, acc10 = {}, acc11 = {};
    #pragma unroll
    for (int s = 0; s < 4; ++s) {
        const int sl = s * 2 + h;
        const int ia0 = ar0 * 64 + ((sl ^ (ar0 & 7)) << 3);
        const int ia1 = ar1 * 64 + ((sl ^ (ar1 & 7)) << 3);
        const int ib0 = bc0 * 64 + ((sl ^ (bc0 & 7)) << 3);
        const int ib1 = bc1 * 64 + ((sl ^ (bc1 & 7)) << 3);
        short8v a0h = *reinterpret_cast<const short8v*>(&Ah[ia0]);
        short8v a1h = *reinterpret_cast<const short8v*>(&Ah[ia1]);
        short8v a0l = *reinterpret_cast<const short8v*>(&Al[ia0]);
        short8v a1l = *reinterpret_cast<const short8v*>(&Al[ia1]);
        short8v b0h = *reinterpret_cast<const short8v*>(&Bh[ib0]);
        short8v b1h = *reinterpret_cast<const short8v*>(&Bh[ib1]);
        short8v b0l = *reinterpret_cast<const short8v*>(&Bl[ib0]);
        short8v b1l = *reinterpret_cast<const short8v*>(&Bl[ib1]);
        acc00 = __builtin_amdgcn_mfma_f32_32x32x16_bf16(a0h, b0h, acc00, 0, 0, 0);
        acc01 = __builtin_amdgcn_mfma_f32_32x32x16_bf16(a0h, b1h, acc01, 0, 0, 0);
        acc10 = __builtin_amdgcn_mfma_f32_32x32x16_bf16(a1h, b0h, acc10, 0, 0, 0);
        acc11 = __builtin_amdgcn_mfma_f32_32x32x16_bf16(a1h, b1h, acc11, 0, 0, 0);
        acc00 = __builtin_amdgcn_mfma_f32_32x32x16_bf16(a0h, b0l, acc00, 0, 0, 0);
        acc01 = __builtin_amdgcn_mfma_f32_32x32x16_bf16(a0h, b1l, acc01, 0, 0, 0);
        acc10 = __builtin_amdgcn_mfma_f32_32x32x16_bf16(a1h, b0l, acc10, 0, 0, 0);
        acc11 = __builtin_amdgcn_mfma_f32_32x32x16_bf16(a1h, b1l, acc11, 0, 0, 0);
        acc00 = __builtin_amdgcn_mfma_f32_32x32x16_bf16(a0l, b0h, acc00, 0, 0, 0);
        acc01 = __builtin_amdgcn_mfma_f32_32x32x16_bf16(a0l, b1h, acc01, 0, 0, 0);
        acc10 = __builtin_amdgcn_mfma_f32_32x32x16_bf16(a1l, b0h, acc10, 0, 0, 0);
        acc11 = __builtin_amdgcn_mfma_f32_32x32x16_bf16(a1l, b1h, acc11, 0, 0, 0);
    }
    const int colg0 = n0 + bc0;
    const int colg1 = n0 + bc1;
    const float sqc0 = sq[bofs + colg0];
    const float sqc1 = sq[bofs + colg1];
    unsigned short* kb = keys + (size_t)blockIdx.y * NP * NP;
    #pragma unroll
    for (int ai = 0; ai < 2; ++ai) {
        const f32x16& A0 = ai ? acc10 : acc00;
        const f32x16& A1 = ai ? acc11 : acc01;
        #pragma unroll
        for (int q = 0; q < 4; ++q) {
            const int rbase = wr * 64 + ai * 32 + 8 * q + 4 * h;   // frag row base
            float sr[4];
            #pragma unroll
            for (int j = 0; j < 4; ++j) sr[j] = sq[bofs + m0 + rbase + j];
            ushort4 s0, s1;
            s0.x = key16(sr[0] + sqc0 - 2.f * A0[q * 4 + 0]);
            s0.y = key16(sr[1] + sqc0 - 2.f * A0[q * 4 + 1]);
            s0.z = key16(sr[2] + sqc0 - 2.f * A0[q * 4 + 2]);
            s0.w = key16(sr[3] + sqc0 - 2.f * A0[q * 4 + 3]);
            s1.x = key16(sr[0] + sqc1 - 2.f * A1[q * 4 + 0]);
            s1.y = key16(sr[1] + sqc1 - 2.f * A1[q * 4 + 1]);
            s1.z = key16(sr[2] + sqc1 - 2.f * A1[q * 4 + 2]);
            s1.w = key16(sr[3] + sqc1 - 2.f * A1[q * 4 + 3]);
            *reinterpret_cast<ushort4*>(&kb[(size_t)colg0 * NP + m0 + rbase]) = s0;
            *reinterpret_cast<ushort4*>(&kb[(size_t)colg1 * NP + m0 + rbase]) = s1;
        }
    }
}

// ---------------- fused select16 + exact refine: wave per query ----------------
// Phase A: cheap bound B = 20th-smallest per-lane min (lane-mins are a 64-elem
//   sub-multiset of the row => B >= exact T16). Bisect costs 1 cmp + ballot/iter.
// Phase B: compact candidates {key16 <= B+6} into wave-local LDS (cap 64).
// Phase C: gather exact f32 keys, rank, emit strict + index-ascending ties.
// Keys loaded as 4x uint4 per lane (16B loads); mapping: kvu[i] holds ushort
// indices 2*(((i>>2)*64+lane)*4 + (i&3)) and +1. Candidate order changes vs
// scalar loads but strict winners are order-free and ties use index-min scan.
template <int D>
__global__ __launch_bounds__(256) void knn_sr_kernel(const unsigned short* __restrict__ keys,
                                                     int b0,
                                                     const float* __restrict__ xf, int ldx,
                                                     const float* __restrict__ sq,
                                                     int* __restrict__ idx_out) {
    constexpr int D4 = D / 4;
    __shared__ int scand[4][64];
    const int tid = threadIdx.x;
    const int w = tid >> 6, lane = tid & 63;
    const int ql = blockIdx.x * 4 + w;        // chunk-local query
    const int bc = ql / NP;
    const int bofs = (b0 + bc) * NP;
    const int q = b0 * NP + ql;               // global query
    const uint4* kr4 = reinterpret_cast<const uint4*>(keys) + (size_t)ql * (NP / 8);

    unsigned kvu[16];
    #pragma unroll
    for (int j = 0; j < 4; ++j) {
        uint4 t = kr4[j * 64 + lane];
        kvu[j * 4 + 0] = t.x; kvu[j * 4 + 1] = t.y;
        kvu[j * 4 + 2] = t.z; kvu[j * 4 + 3] = t.w;
    }

    unsigned lmn = 0xFFFFu;
    #pragma unroll
    for (int v = 0; v < 16; ++v) {
        lmn = min(lmn, kvu[v] & 0xFFFFu);
        lmn = min(lmn, kvu[v] >> 16);
    }
    unsigned lo = lmn, hi = lmn;
    #pragma unroll
    for (int s = 1; s < 64; s <<= 1) {
        lo = min(lo, __shfl_xor(lo, s));
        hi = max(hi, __shfl_xor(hi, s));
    }
    while (lo < hi) {
        unsigned mid = (lo + hi) >> 1;
        int c = __popcll(__ballot(lmn <= mid));
        if (c >= KK) hi = mid; else lo = mid + 1;
    }
    const unsigned T = min(lo + 6u, 0xFFFFu);   // B >= T16; +6 covers MFMA approx error

    unsigned nl = 0;
    #pragma unroll
    for (int v = 0; v < 16; ++v) {
        nl += ((kvu[v] & 0xFFFFu) <= T) ? 1u : 0u;
        nl += ((kvu[v] >> 16) <= T) ? 1u : 0u;
    }
    unsigned sc = nl;
    #pragma unroll
    for (int s = 1; s < 64; s <<= 1) {
        unsigned t2 = __shfl_up(sc, s);
        if (lane >= s) sc += t2;
    }
    const int cnt = (int)__shfl(sc, 63);
    unsigned off = sc - nl;
    #pragma unroll
    for (int v = 0; v < 16; ++v) {
        const int ub = ((v >> 2) * 64 + lane) * 4 + (v & 3);   // uint index in row
        if ((kvu[v] & 0xFFFFu) <= T) { if (off < 64u) scand[w][off] = bofs + ub * 2; ++off; }
        if ((kvu[v] >> 16) <= T)     { if (off < 64u) scand[w][off] = bofs + ub * 2 + 1; ++off; }
    }

    float4 qv[D4];
    const float4* xq4 = reinterpret_cast<const float4*>(xf + (size_t)q * ldx);
    #pragma unroll
    for (int k = 0; k < D4; ++k) qv[k] = xq4[k];
    const float sqq = sq[q];
    int* op = idx_out + (size_t)q * KK;

    if (cnt <= 64) {
        const int cidx = (lane < cnt) ? scand[w][lane] : -1;
        unsigned key = 0xFFFFFFFFu;
        if (cidx >= 0) {
            const float4* xc4 = reinterpret_cast<const float4*>(xf + (size_t)cidx * ldx);
            float acc = 0.f;
            #pragma unroll
            for (int k = 0; k < D4; ++k) {
                float4 c = xc4[k];
                acc += qv[k].x * c.x; acc += qv[k].y * c.y;
                acc += qv[k].z * c.z; acc += qv[k].w * c.w;
            }
            key = mono_key(sqq + sq[cidx] - 2.f * acc);
        }
        unsigned klo = key, khi = key;
        #pragma unroll
        for (int s = 1; s < 64; s <<= 1) {
            klo = min(klo, __shfl_xor(klo, s));
            khi = max(khi, __shfl_xor(khi, s));
        }
        while (klo < khi) {
            unsigned mid = klo + ((khi - klo) >> 1);
            int c = __popcll(__ballot(key <= mid));
            if (c >= KK) khi = mid; else klo = mid + 1;
        }
        const unsigned Tx = klo;
        unsigned long long blt = __ballot(key < Tx);
        const int strict = __popcll(blt);
        if (key < Tx) {
            int o = __popcll(blt & ((1ull << lane) - 1ull));
            op[o] = cidx;
        }
        const int rem = KK - strict;
        bool eq = (key == Tx) && (cidx >= 0);
        bool done = false;
        for (int t = 0; t < rem; ++t) {   // emit ties in ascending global index order
            int v = (eq && !done) ? cidx : 0x7FFFFFFF;
            #pragma unroll
            for (int s = 1; s < 64; s <<= 1) v = min(v, __shfl_xor(v, s));
            if (eq && !done && cidx == v) { op[strict + t] = cidx; done = true; }
        }
    } else {
        // fallback: exact full-row scan (deterministic; ~never taken)
        unsigned keysr[32];
        for (int u = 0; u < 32; ++u) {
            const int c = bofs + u * 64 + lane;
            const float4* xc4 = reinterpret_cast<const float4*>(xf + (size_t)c * ldx);
            float acc = 0.f;
            #pragma unroll
            for (int k = 0; k < D4; ++k) {
                float4 cv = xc4[k];
                acc += qv[k].x * cv.x; acc += qv[k].y * cv.y;
                acc += qv[k].z * cv.z; acc += qv[k].w * cv.w;
            }
            keysr[u] = mono_key(sqq + sq[c] - 2.f * acc);
        }
        unsigned lmn2 = 0xFFFFFFFFu;
        #pragma unroll
        for (int u = 0; u < 32; ++u) lmn2 = min(lmn2, keysr[u]);
        unsigned M2 = lmn2, lo2 = lmn2;
        #pragma unroll
        for (int s = 1; s < 64; s <<= 1) {
            unsigned tM = __shfl_xor(M2, s);
            unsigned tl = __shfl_xor(lo2, s);
            M2 = max(M2, tM);
            lo2 = min(lo2, tl);
        }
        unsigned hi2 = M2;
        while (lo2 < hi2) {
            unsigned mid = lo2 + ((hi2 - lo2) >> 1);
            int c = 0;
            #pragma unroll
            for (int u = 0; u < 32; ++u)
                c += __popcll(__ballot(keysr[u] <= mid));
            if (c >= KK) hi2 = mid; else lo2 = mid + 1;
        }
        const unsigned Tx = lo2;
        unsigned nl2 = 0;
        #pragma unroll
        for (int u = 0; u < 32; ++u) nl2 += (keysr[u] < Tx) ? 1u : 0u;
        unsigned sc2 = nl2;
        #pragma unroll
        for (int s = 1; s < 64; s <<= 1) {
            unsigned t2 = __shfl_up(sc2, s);
            if (lane >= s) sc2 += t2;
        }
        unsigned cstrict = __shfl(sc2, 63);
        unsigned o = sc2 - nl2;
        #pragma unroll
        for (int u = 0; u < 32; ++u) {
            if (keysr[u] < Tx) { op[o] = bofs + u * 64 + lane; ++o; }
        }
        int rem = KK - (int)cstrict;
        int ebase = (int)cstrict;
        #pragma unroll
        for (int u = 0; u < 32; ++u) {
            if (rem > 0) {
                bool eq = (keysr[u] == Tx);
                unsigned long long bm = __ballot(eq);
                int before = __popcll(bm & ((1ull << lane) - 1ull));
                if (eq && before < rem) op[ebase + before] = bofs + u * 64 + lane;
                int take = __popcll(bm);
                if (take > rem) take = rem;
                ebase += take;
                rem -= take;
            }
        }
    }
}

// ---------------- Wt[c][j] build: [Wd | Wtail] transposed, zero-padded ----------------
__global__ __launch_bounds__(256) void wt_build_kernel(const float* __restrict__ W,
                                                       float* __restrict__ Wt,
                                                       int D, int Dp, int C) {
    int i = blockIdx.x * 256 + threadIdx.x;
    if (i < 2 * C * Dp) {
        int c = i / Dp, j = i % Dp;
        float v = 0.f;
        if (j < D) {
            v = (c < C) ? (W[j * C + c] - W[(D + j) * C + c])
                        : W[(D + j) * C + (c - C)];
        }
        Wt[i] = v;
    }
}

// ---------------- X[TOT,Dp] @ Wt^T -> basexw[TOT,2C] ----------------
template <int NJ4, int C2>
__global__ __launch_bounds__(256) void xw_gemm_kernel(const float* __restrict__ x, int ldx,
                                                      const float* __restrict__ Wt,
                                                      float* __restrict__ bx) {
    constexpr int PG = 256 / C2;   // point groups
    constexpr int PTS = 16 / PG;   // points per thread
    __shared__ float4 Xs[16][NJ4];
    const int tid = threadIdx.x;
    const int p0 = blockIdx.x * 16;
    for (int i = tid; i < 16 * NJ4; i += 256) {
        int r = i / NJ4, j4 = i % NJ4;
        Xs[r][j4] = *reinterpret_cast<const float4*>(x + (size_t)(p0 + r) * ldx + j4 * 4);
    }
    __syncthreads();
    const int c = tid % C2, pg = tid / C2;
    const float4* wrow = reinterpret_cast<const float4*>(Wt + (size_t)c * (NJ4 * 4));
    float acc[PTS];
    #pragma unroll
    for (int u = 0; u < PTS; ++u) acc[u] = 0.f;
    #pragma unroll
    for (int j4 = 0; j4 < NJ4; ++j4) {
        float4 w4 = wrow[j4];
        #pragma unroll
        for (int u = 0; u < PTS; ++u) {
            float4 x4 = Xs[pg * PTS + u][j4];
            acc[u] += x4.x * w4.x + x4.y * w4.y + x4.z * w4.z + x4.w * w4.w;
        }
    }
    #pragma unroll
    for (int u = 0; u < PTS; ++u)
        bx[(size_t)(p0 + pg * PTS + u) * C2 + c] = acc[u];
}

// ---------------- edge pass: gather XW, stats + per-point max/min ----------------
template <int C>
__global__ __launch_bounds__(256) void edge_pass_kernel(const float* __restrict__ bx,
                                                        const int* __restrict__ idx,
                                                        float* __restrict__ psum,
                                                        float* __restrict__ psum2,
                                                        float* __restrict__ mmax,
                                                        float* __restrict__ mmin) {
    constexpr int PT = 256 / C;
    constexpr int C2 = 2 * C;
    __shared__ int sidx[PT][KK];
    __shared__ float red[256];
    const int tid = threadIdx.x;
    const int c = tid % C;
    const int pl = tid / C;
    float s1 = 0.f, s2 = 0.f;
    const int NT = TOT / PT;
    for (int t = blockIdx.x; t < NT; t += EBLK) {
        const int p0 = t * PT;
        __syncthreads();
        if (tid < PT * KK) sidx[tid / KK][tid % KK] = idx[(size_t)p0 * KK + tid];
        __syncthreads();
        const int p = p0 + pl;
        const float bv = bx[(size_t)p * C2 + c];
        float A = 0.f, Q = 0.f, M = -FLT_MAX, mn = FLT_MAX;
        #pragma unroll
        for (int k = 0; k < KK; ++k) {
            float v = bx[(size_t)sidx[pl][k] * C2 + C + c];
            A += v; Q += v * v; M = fmaxf(M, v); mn = fminf(mn, v);
        }
        s1 += (float)KK * bv + A;
        s2 += (float)KK * bv * bv + 2.f * bv * A + Q;
        mmax[(size_t)p * C + c] = bv + M;
        mmin[(size_t)p * C + c] = bv + mn;
    }
    red[tid] = s1;
    __syncthreads();
    if (tid < C) {
        float v = red[tid];
        #pragma unroll
        for (int u = 1; u < PT; ++u) v += red[tid + u * C];
        psum[(size_t)blockIdx.x * C + tid] = v;
    }
    __syncthreads();
    red[tid] = s2;
    __syncthreads();
    if (tid < C) {
        float v = red[tid];
        #pragma unroll
        for (int u = 1; u < PT; ++u) v += red[tid + u * C];
        psum2[(size_t)blockIdx.x * C + tid] = v;
    }
}

// ---------------- BN stats reduce -> alpha/beta ----------------
__global__ __launch_bounds__(256) void bn_reduce_kernel(
        const float* __restrict__ psum, const float* __restrict__ psum2,
        int npart, int C, const float* __restrict__ g, const float* __restrict__ bb,
        float inv_cnt, float* __restrict__ alpha, float* __restrict__ beta) {
    const int c = blockIdx.x;
    const int tid = threadIdx.x;
    __shared__ float r1[256], r2[256];
    float s1 = 0.f, s2 = 0.f;
    for (int i = tid; i < npart; i += 256) {
        s1 += psum[(size_t)i * C + c];
        s2 += psum2[(size_t)i * C + c];
    }
    r1[tid] = s1; r2[tid] = s2;
    __syncthreads();
    for (int s = 128; s > 0; s >>= 1) {
        if (tid < s) { r1[tid] += r1[tid + s]; r2[tid] += r2[tid + s]; }
        __syncthreads();
    }
    if (tid == 0) {
        float mean = r1[0] * inv_cnt;
        float var = r2[0] * inv_cnt - mean * mean;
        float a = g[c] * rsqrtf(var + 1e-5f);
        alpha[c] = a;
        beta[c] = bb[c] - mean * a;
    }
}

// ---------------- edge finalize: pick by sign(alpha), affine+leaky; f32 + bf16 hi/lo (+sq) ----------------
template <int C>
__global__ __launch_bounds__(256) void edge_finalize_kernel(const float* __restrict__ mmax,
                                                            const float* __restrict__ mmin,
                                                            const float* __restrict__ alpha,
                                                            const float* __restrict__ beta,
                                                            float* __restrict__ xcf, int ldf,
                                                            unsigned short* __restrict__ xch,
                                                            unsigned short* __restrict__ xcl,
                                                            int ch_off,
                                                            float* __restrict__ sq_out) {
    constexpr int CQ = C / 4;
    __shared__ float red[256];
    const int tid = threadIdx.x;
    int i4 = blockIdx.x * 256 + tid;
    float4 o = make_float4(0.f, 0.f, 0.f, 0.f);
    int p = 0;
    if (i4 < TOT * CQ) {
        int cq; p = i4 / CQ; cq = i4 - p * CQ;
        float4 M4 = reinterpret_cast<const float4*>(mmax)[i4];
        float4 m4 = reinterpret_cast<const float4*>(mmin)[i4];
        float4 a4 = reinterpret_cast<const float4*>(alpha)[cq];
        float4 b4 = reinterpret_cast<const float4*>(beta)[cq];
        o.x = leaky(a4.x * (a4.x >= 0.f ? M4.x : m4.x) + b4.x);
        o.y = leaky(a4.y * (a4.y >= 0.f ? M4.y : m4.y) + b4.y);
        o.z = leaky(a4.z * (a4.z >= 0.f ? M4.z : m4.z) + b4.z);
        o.w = leaky(a4.w * (a4.w >= 0.f ? M4.w : m4.w) + b4.w);
        if (xcf)
            *reinterpret_cast<float4*>(xcf + (size_t)p * ldf + cq * 4) = o;
        ushort4 hh, ll;
        hh.x = bf16_rne(o.x); ll.x = bf16_rne(o.x - bf16_f(hh.x));
        hh.y = bf16_rne(o.y); ll.y = bf16_rne(o.y - bf16_f(hh.y));
        hh.z = bf16_rne(o.z); ll.z = bf16_rne(o.z - bf16_f(hh.z));
        hh.w = bf16_rne(o.w); ll.w = bf16_rne(o.w - bf16_f(hh.w));
        const size_t oo = (size_t)p * 256 + ch_off + cq * 4;
        *reinterpret_cast<ushort4*>(xch + oo) = hh;
        *reinterpret_cast<ushort4*>(xcl + oo) = ll;
    }
    if (sq_out) {   // only used for C=64 (CQ=16, 16 pts/block, exact grid)
        red[tid] = o.x * o.x + o.y * o.y + o.z * o.z + o.w * o.w;
        __syncthreads();
        if ((tid & (CQ - 1)) == 0) {
            float s = red[tid];
            #pragma unroll
            for (int u = 1; u < CQ; ++u) s += red[tid + u];
            sq_out[p] = s;
        }
    }
}

// ---------------- Wf -> bf16 hi/lo, transposed to [1024][256] ----------------
__global__ __launch_bounds__(256) void wfhl_build_kernel(const float* __restrict__ Wf,
                                                         unsigned short* __restrict__ wfh,
                                                         unsigned short* __restrict__ wfl) {
    int i = blockIdx.x * 256 + threadIdx.x;
    if (i < 256 * 1024) {
        int e = i / 1024, o = i - e * 1024;
        float v = Wf[i];
        unsigned short h = bf16_rne(v);
        wfh[(size_t)o * 256 + e] = h;
        wfl[(size_t)o * 256 + e] = bf16_rne(v - bf16_f(h));
    }
}

// ---------------- conv_final via MFMA bf16x3 + stat partials ----------------
__global__ __launch_bounds__(256) void fc_mfma_kernel(const unsigned short* __restrict__ xch,
                                                      const unsigned short* __restrict__ xcl,
                                                      const unsigned short* __restrict__ wfh,
                                                      const unsigned short* __restrict__ wfl,
                                                      float* __restrict__ psum,
                                                      float* __restrict__ psum2,
                                                      float* __restrict__ pmax,
                                                      float* __restrict__ pmin) {
    __shared__ __align__(16) unsigned short Ah[128 * 64];
    __shared__ __align__(16) unsigned short Al[128 * 64];
    __shared__ __align__(16) unsigned short Bh[128 * 64];
    __shared__ __align__(16) unsigned short Bl[128 * 64];
    const int tid = threadIdx.x;
    const int w = tid >> 6, lane = tid & 63;
    const int wr = w >> 1, wc = w & 1;
    const int pt = blockIdx.x, ct = blockIdx.y;
    f32x16 acc00 = {}, acc01 = {}, acc10 = {}, acc11 = {};
    for (int kc = 0; kc < 4; ++kc) {
        const int k0 = kc * 64;
        __syncthreads();
        for (int i = tid; i < 1024; i += 256) {
            const int r = i >> 3, slot = i & 7;
            const int ls = r * 64 + ((slot ^ (r & 7)) << 3);
            const size_t ga = (size_t)(pt * 128 + r) * 256 + k0 + slot * 8;
            const size_t gb = (size_t)(ct * 128 + r) * 256 + k0 + slot * 8;
            *reinterpret_cast<uint4*>(&Ah[ls]) = *reinterpret_cast<const uint4*>(&xch[ga]);
            *reinterpret_cast<uint4*>(&Al[ls]) = *reinterpret_cast<const uint4*>(&xcl[ga]);
            *reinterpret_cast<uint4*>(&Bh[ls]) = *reinterpret_cast<const uint4*>(&wfh[gb]);
            *reinterpret_cast<uint4*>(&Bl[ls]) = *reinterpret_cast<const uint4*>(&wfl[gb]);
        }
        __syncthreads();
        const int h = lane >> 5;
        const int ar0 = wr * 64 + (lane & 31), ar1 = ar0 + 32;
        const int bc0 = wc * 64 + (lane & 31), bc1 = bc0 + 32;
        #pragma unroll
        for (int s = 0; s < 4; ++s) {
            const int sl = s * 2 + h;
            const int ia0 = ar0 * 64 + ((sl ^ (ar0 & 7)) << 3);
            const int ia1 = ar1 * 64 + ((sl ^ (ar1 & 7)) << 3);
            const int ib0 = bc0 * 64 + ((sl ^ (bc0 & 7)) << 3);
            const int ib1 = bc1 * 64 + ((sl ^ (bc1 & 7)) << 3);
            short8v a0h = *reinterpret_cast<const short8v*>(&Ah[ia0]);
            short8v a1h = *reinterpret_cast<const short8v*>(&Ah[ia1]);
            short8v a0l = *reinterpret_cast<const short8v*>(&Al[ia0]);
            short8v a1l = *reinterpret_cast<const short8v*>(&Al[ia1]);
            short8v b0h = *reinterpret_cast<const short8v*>(&Bh[ib0]);
            short8v b1h = *reinterpret_cast<const short8v*>(&Bh[ib1]);
            short8v b0l = *reinterpret_cast<const short8v*>(&Bl[ib0]);
            short8v b1l = *reinterpret_cast<const short8v*>(&Bl[ib1]);
            acc00 = __builtin_amdgcn_mfma_f32_32x32x16_bf16(a0h, b0h, acc00, 0, 0, 0);
            acc01 = __builtin_amdgcn_mfma_f32_32x32x16_bf16(a0h, b1h, acc01, 0, 0, 0);
            acc10 = __builtin_amdgcn_mfma_f32_32x32x16_bf16(a1h, b0h, acc10, 0, 0, 0);
            acc11 = __builtin_amdgcn_mfma_f32_32x32x16_bf16(a1h, b1h, acc11, 0, 0, 0);
            acc00 = __builtin_amdgcn_mfma_f32_32x32x16_bf16(a0h, b0l, acc00, 0, 0, 0);
            acc01 = __builtin_amdgcn_mfma_f32_32x32x16_bf16(a0h, b1l, acc01, 0, 0, 0);
            acc10 = __builtin_amdgcn_mfma_f32_32x32x16_bf16(a1h, b0l, acc10, 0, 0, 0);
            acc11 = __builtin_amdgcn_mfma_f32_32x32x16_bf16(a1h, b1l, acc11, 0, 0, 0);
            acc00 = __builtin_amdgcn_mfma_f32_32x32x16_bf16(a0l, b0h, acc00, 0, 0, 0);
            acc01 = __builtin_amdgcn_mfma_f32_32x32x16_bf16(a0l, b1h, acc01, 0, 0, 0);
            acc10 = __builtin_amdgcn_mfma_f32_32x32x16_bf16(a1l, b0h, acc10, 0, 0, 0);
            acc11 = __builtin_amdgcn_mfma_f32_32x32x16_bf16(a1l, b1h, acc11, 0, 0, 0);
        }
    }
    float* red = reinterpret_cast<float*>(Ah);   // [2 wr][128 ch][4 stats]
    __syncthreads();
    #pragma unroll
    for (int fc = 0; fc < 2; ++fc) {
        float s1 = 0.f, s2 = 0.f, mx = -FLT_MAX, mn = FLT_MAX;
        #pragma unroll
        for (int e = 0; e < 16; ++e) {
            float v0 = (fc == 0) ? acc00[e] : acc01[e];
            float v1 = (fc == 0) ? acc10[e] : acc11[e];
            s1 += v0 + v1;
            s2 += v0 * v0 + v1 * v1;
            mx = fmaxf(mx, fmaxf(v0, v1));
            mn = fminf(mn, fminf(v0, v1));
        }
        s1 += __shfl_xor(s1, 32);
        s2 += __shfl_xor(s2, 32);
        mx = fmaxf(mx, __shfl_xor(mx, 32));
        mn = fminf(mn, __shfl_xor(mn, 32));
        if (lane < 32) {
            const int ch = wc * 64 + fc * 32 + lane;
            float4 st; st.x = s1; st.y = s2; st.z = mx; st.w = mn;
            *reinterpret_cast<float4*>(&red[(wr * 128 + ch) * 4]) = st;
        }
    }
    __syncthreads();
    if (tid < 128) {
        float4 s0 = *reinterpret_cast<const float4*>(&red[tid * 4]);
        float4 s1 = *reinterpret_cast<const float4*>(&red[(128 + tid) * 4]);
        const size_t go = (size_t)pt * 1024 + ct * 128 + tid;
        psum[go]  = s0.x + s1.x;
        psum2[go] = s0.y + s1.y;
        pmax[go]  = fmaxf(s0.z, s1.z);
        pmin[go]  = fminf(s0.w, s1.w);
    }
}

// ---------------- gfeat finalize (16 point-tile partials per batch) ----------------
__global__ __launch_bounds__(256) void gfeat_final_kernel(const float* __restrict__ pmax,
                                                          const float* __restrict__ pmin,
                                                          const float* __restrict__ alpha,
                                                          const float* __restrict__ beta,
                                                          float* __restrict__ gfeat) {
    int i = blockIdx.x * 256 + threadIdx.x;
    if (i < NB * 1024) {
        int b = i >> 10, c = i & 1023;
        float mx = -FLT_MAX, mn = FLT_MAX;
        for (int j = 0; j < 16; ++j) {
            size_t o = (size_t)(b * 16 + j) * 1024 + c;
            mx = fmaxf(mx, pmax[o]);
            mn = fminf(mn, pmin[o]);
        }
        float a = alpha[c];
        gfeat[i] = leaky(a * (a >= 0.f ? mx : mn) + beta[c]);
    }
}

// ---------------- classifier: split-K skinny GEMM, A is [16][K] ----------------
template <int CHUNK>
__global__ __launch_bounds__(256) void skinny_gemm_kernel(const float* __restrict__ A,
                                                          const float* __restrict__ W,
                                                          float* __restrict__ part,
                                                          int K, int N) {
    __shared__ float Asub[4][16][CHUNK];
    const int tid = threadIdx.x;
    const int g = tid >> 6, lane = tid & 63;
    const int c = blockIdx.x * 64 + lane;
    const int ks = blockIdx.y * 4 + g;
    const int e0 = ks * CHUNK;
    for (int i = lane; i < 16 * CHUNK; i += 64) {
        const int m = i / CHUNK, el = i - m * CHUNK;
        Asub[g][m][el] = A[(size_t)m * K + e0 + el];
    }
    if (c < N) {
        float acc[16];
        #pragma unroll
        for (int m = 0; m < 16; ++m) acc[m] = 0.f;
        #pragma unroll 4
        for (int el = 0; el < CHUNK; ++el) {
            float w = W[(size_t)(e0 + el) * N + c];
            #pragma unroll
            for (int m = 0; m < 16; ++m) acc[m] += Asub[g][m][el] * w;
        }
        #pragma unroll
        for (int m = 0; m < 16; ++m)
            part[((size_t)ks * 16 + m) * N + c] = acc[m];
    }
}

// ---------------- classifier finish: reduce splits + bias (+BN over rows + leaky) ----------------
__global__ __launch_bounds__(256) void fin_kernel(const float* __restrict__ part,
                                                  int S, int N,
                                                  const float* __restrict__ bias,
                                                  const float* __restrict__ g,
                                                  const float* __restrict__ bb,
                                                  int do_bn,
                                                  float* __restrict__ out, int Nout) {
    int c = blockIdx.x * 256 + threadIdx.x;
    if (c >= N) return;
    float z[16];
    #pragma unroll
    for (int m = 0; m < 16; ++m) z[m] = bias[c];
    for (int s = 0; s < S; ++s)
        #pragma unroll
        for (int m = 0; m < 16; ++m) z[m] += part[((size_t)s * 16 + m) * N + c];
    if (do_bn) {
        float s1 = 0.f, s2 = 0.f;
        #pragma unroll
        for (int m = 0; m < 16; ++m) { s1 += z[m]; s2 += z[m] * z[m]; }
        float mean = s1 * (1.f / 16.f);
        float var = s2 * (1.f / 16.f) - mean * mean;
        float a = g[c] * rsqrtf(var + 1e-5f);
        float be = bb[c] - mean * a;
        #pragma unroll
        for (int m = 0; m < 16; ++m) out[(size_t)m * N + c] = leaky(a * z[m] + be);
    } else {
        if (c < Nout)
            #pragma unroll
            for (int m = 0; m < 16; ++m) out[(size_t)m * Nout + c] = z[m];
    }
}

static void run_knn_l1(const float* x, const float* sq, unsigned short* keys16, int CB,
                       int* idx, hipStream_t stream) {
    for (int b0 = 0; b0 < NB; b0 += CB) {
        dim3 g(136, CB);   // lower-triangle tile pairs
        dist_sym16_kernel<4><<<g, 256, 0, stream>>>(x, 4, sq, b0, keys16);
        knn_sr_kernel<4><<<CB * NP / 4, 256, 0, stream>>>(keys16, b0, x, 4, sq, idx);
    }
}

static void run_knn_feat(const unsigned short* xh, const unsigned short* xl, int ch_off,
                         const float* xf, const float* sq, unsigned short* keys16, int CB,
                         int* idx, hipStream_t stream) {
    for (int b0 = 0; b0 < NB; b0 += CB) {
        dim3 g(256, CB);   // full tile grid
        dist_mfma16_kernel<<<g, 256, 0, stream>>>(xh, xl, ch_off, sq, b0, keys16);
        knn_sr_kernel<64><<<CB * NP / 4, 256, 0, stream>>>(keys16, b0, xf, 128, sq, idx);
    }
}

} // namespace

extern "C" void kernel_launch(void* const* d_in, const int* in_sizes, int n_in,
                              void* d_out, int out_size, void* d_ws, size_t ws_size,
                              hipStream_t stream) {
    (void)in_sizes; (void)n_in; (void)out_size;
    const float* pos = (const float*)d_in[0];
    const float* W1  = (const float*)d_in[1];
    const float* g1  = (const float*)d_in[2];
    const float* b1  = (const float*)d_in[3];
    const float* W2  = (const float*)d_in[4];
    const float* g2  = (const float*)d_in[5];
    const float* b2  = (const float*)d_in[6];
    const float* W3  = (const float*)d_in[7];
    const float* g3  = (const float*)d_in[8];
    const float* b3  = (const float*)d_in[9];
    const float* Wf  = (const float*)d_in[10];
    const float* gf  = (const float*)d_in[11];
    const float* bf  = (const float*)d_in[12];
    const float* W4  = (const float*)d_in[13];
    const float* b4  = (const float*)d_in[14];
    const float* g4  = (const float*)d_in[15];
    const float* be4 = (const float*)d_in[16];
    const float* W5  = (const float*)d_in[17];
    const float* b5  = (const float*)d_in[18];
    const float* g5  = (const float*)d_in[19];
    const float* be5 = (const float*)d_in[20];
    const float* W6  = (const float*)d_in[21];
    const float* b6  = (const float*)d_in[22];
    float* out = (float*)d_out;

    float* ws = (float*)d_ws;
    size_t off = 0;
    int*   idx    = (int*)ws;      off += (size_t)TOT * KK;          // 2.6 MB
    float* pos4   = ws + off;      off += (size_t)TOT * 4;
    float* sq     = ws + off;      off += (size_t)TOT;
    float* Wt     = ws + off;      off += 256 * 64;
    float* basexw = ws + off;      off += (size_t)TOT * 256;         // 32 MB
    float* mmax   = ws + off;      off += (size_t)TOT * 128;         // 16 MB
    float* mmin   = ws + off;      off += (size_t)TOT * 128;         // 16 MB
    float* xc12   = ws + off;      off += (size_t)TOT * 128;         // 16 MB (x1|x2 f32)
    unsigned short* xch = (unsigned short*)(ws + off); off += (size_t)TOT * 128;  // 16 MB bf16 hi
    unsigned short* xcl = (unsigned short*)(ws + off); off += (size_t)TOT * 128;  // 16 MB bf16 lo
    unsigned short* wfh = (unsigned short*)(ws + off); off += (size_t)1024 * 128;
    unsigned short* wfl = (unsigned short*)(ws + off); off += (size_t)1024 * 128;
    float* psum   = ws + off;      off += (size_t)512 * 1024;        // 2 MB
    float* psum2  = ws + off;      off += (size_t)512 * 1024;
    float* pmax   = ws + off;      off += (size_t)512 * 1024;
    float* pmin   = ws + off;      off += (size_t)512 * 1024;
    float* alpha  = ws + off;      off += 1024;
    float* beta   = ws + off;      off += 1024;
    float* gfeat  = ws + off;      off += NB * 1024;
    float* part   = ws + off;      off += 8 * 16 * 512;              // split-K partials
    float* h4     = ws + off;      off += NB * 512;
    float* h5     = ws + off;      off += NB * 256;
    unsigned short* keys16 = (unsigned short*)(ws + off);
    const size_t avail = (ws_size > off * 4) ? (ws_size - off * 4) : 0;
    const size_t per_batch = (size_t)NP * NP * 2;   // 16-bit keys
    int CB = 1;
    for (int cb : {8, 4, 2}) {     // keys16 <= 64 MB, L3-resident
        if ((size_t)cb * per_batch <= avail) { CB = cb; break; }
    }

    const int npts_blk = (TOT + 255) / 256;

    // ---------- Layer 1 (D=3 padded to 4, C=64) ----------
    pos4sq_kernel<<<npts_blk, 256, 0, stream>>>(pos, pos4, sq);
    run_knn_l1(pos4, sq, keys16, CB, idx, stream);
    wt_build_kernel<<<2, 256, 0, stream>>>(W1, Wt, 3, 4, 64);
    xw_gemm_kernel<1, 128><<<TOT / 16, 256, 0, stream>>>(pos4, 4, Wt, basexw);
    edge_pass_kernel<64><<<EBLK, 256, 0, stream>>>(basexw, idx, psum, psum2, mmax, mmin);
    bn_reduce_kernel<<<64, 256, 0, stream>>>(psum, psum2, EBLK, 64, g1, b1,
                                             1.f / (float)(TOT * KK), alpha, beta);
    edge_finalize_kernel<64><<<TOT * 16 / 256, 256, 0, stream>>>(
        mmax, mmin, alpha, beta, xc12 + 0, 128, xch, xcl, 0, sq);   // sq for layer 2

    // ---------- Layer 2 (D=64, C=64), input x1 = xc12[:,0:64] / xch[:,0:64] ----------
    run_knn_feat(xch, xcl, 0, xc12 + 0, sq, keys16, CB, idx, stream);
    wt_build_kernel<<<32, 256, 0, stream>>>(W2, Wt, 64, 64, 64);
    xw_gemm_kernel<16, 128><<<TOT / 16, 256, 0, stream>>>(xc12 + 0, 128, Wt, basexw);
    edge_pass_kernel<64><<<EBLK, 256, 0, stream>>>(basexw, idx, psum, psum2, mmax, mmin);
    bn_reduce_kernel<<<64, 256, 0, stream>>>(psum, psum2, EBLK, 64, g2, b2,
                                             1.f / (float)(TOT * KK), alpha, beta);
    edge_finalize_kernel<64><<<TOT * 16 / 256, 256, 0, stream>>>(
        mmax, mmin, alpha, beta, xc12 + 64, 128, xch, xcl, 64, sq); // sq for layer 3

    // ---------- Layer 3 (D=64, C=128), input x2 = xc12[:,64:128] / xch[:,64:128] ----------
    run_knn_feat(xch, xcl, 64, xc12 + 64, sq, keys16, CB, idx, stream);
    wt_build_kernel<<<64, 256, 0, stream>>>(W3, Wt, 64, 64, 128);
    xw_gemm_kernel<16, 256><<<TOT / 16, 256, 0, stream>>>(xc12 + 64, 128, Wt, basexw);
    edge_pass_kernel<128><<<EBLK, 256, 0, stream>>>(basexw, idx, psum, psum2, mmax, mmin);
    bn_reduce_kernel<<<128, 256, 0, stream>>>(psum, psum2, EBLK, 128, g3, b3,
                                              1.f / (float)(TOT * KK), alpha, beta);
    edge_finalize_kernel<128><<<TOT * 32 / 256, 256, 0, stream>>>(
        mmax, mmin, alpha, beta, nullptr, 0, xch, xcl, 128, nullptr);

    // ---------- conv_final (MFMA bf16x3) + global max pool ----------
    wfhl_build_kernel<<<1024, 256, 0, stream>>>(Wf, wfh, wfl);
    {
        dim3 g(TOT / 128, 8, 1);
        fc_mfma_kernel<<<g, 256, 0, stream>>>(xch, xcl, wfh, wfl, psum, psum2, pmax, pmin);
    }
    bn_reduce_kernel<<<1024, 256, 0, stream>>>(psum, psum2, 256, 1024, gf, bf,
                                               1.f / (float)TOT, alpha, beta);
    gfeat_final_kernel<<<64, 256, 0, stream>>>(pmax, pmin, alpha, beta, gfeat);

    // ---------- classifier (split-K skinny GEMMs) ----------
    skinny_gemm_kernel<128><<<dim3(8, 2), 256, 0, stream>>>(gfeat, W4, part, 1024, 512);
    fin_kernel<<<2, 256, 0, stream>>>(part, 8, 512, b4, g4, be4, 1, h4, 512);
    skinny_gemm_kernel<64><<<dim3(4, 2), 256, 0, stream>>>(h4, W5, part, 512, 256);
    fin_kernel<<<1, 256, 0, stream>>>(part, 8, 256, b5, g5, be5, 1, h5, 256);
    skinny_gemm_kernel<32><<<dim3(1, 2), 256, 0, stream>>>(h5, W6, part, 256, 40);
    fin_kernel<<<1, 256, 0, stream>>>(part, 8, 40, b6, nullptr, nullptr, 0, out, 40);
}